// Round 3
// baseline (468.206 us; speedup 1.0000x reference)
//
#include <hip/hip_runtime.h>

typedef short bf16x8 __attribute__((ext_vector_type(8)));
typedef float f32x4 __attribute__((ext_vector_type(4)));
typedef unsigned short u16x4 __attribute__((ext_vector_type(4)));

static constexpr int N_NODES = 50000;
static constexpr int N_EDGES = 800000;
static constexpr int D_NODE = 128;
static constexpr int D_EDGE = 64;

__device__ __forceinline__ unsigned short f2bf(float f) {
    union { float f; unsigned u; } v; v.f = f;
    return (unsigned short)((v.u + 0x7fffu + ((v.u >> 16) & 1u)) >> 16);
}

// ---------------- kernel 0: acc = node_feat ((1+eps)*x term, eps=0) ----------
__global__ void k_copy(const f32x4* __restrict__ s, f32x4* __restrict__ d, int n4) {
    int stride = gridDim.x * blockDim.x;
    for (int i = blockIdx.x * blockDim.x + threadIdx.x; i < n4; i += stride)
        d[i] = s[i];
}

// ---------------- kernel 1: edge MLP + gather + scatter-atomic ----------------
// wave handles 4 tiles of 16 edges; W0/W1 staged in LDS in MFMA fragment order.
__global__ __launch_bounds__(256) void k_edge(
    const float* __restrict__ ef, const float* __restrict__ nf,
    const float* __restrict__ W0, const float* __restrict__ b0,
    const float* __restrict__ W1, const float* __restrict__ b1,
    const int* __restrict__ src, const int* __restrict__ dst,
    float* __restrict__ acc)
{
    __shared__ unsigned short w0f[2 * 4 * 64 * 8];   // 8 KB  : [ks][nt][lane][8]
    __shared__ unsigned short w1f[2 * 8 * 64 * 8];   // 16 KB : [ks][nt][lane][8]
    __shared__ unsigned short hT[4][16][72];         // per-wave h tile, +8 pad

    const int tid = threadIdx.x;
    // stage W0 fragments: elem j of lane's frag is W[k][n],
    // k = ks*32 + (lane>>4)*4 + (j&3) + (j>=4 ? 16 : 0), n = nt*16 + (lane&15)
    for (int f = tid; f < 4096; f += 256) {
        int j = f & 7, lane = (f >> 3) & 63, nt = (f >> 9) & 3, ks = (f >> 11) & 1;
        int k = ks * 32 + ((lane >> 4) << 2) + (j & 3) + ((j & 4) << 2);
        int n = nt * 16 + (lane & 15);
        w0f[f] = f2bf(W0[k * 64 + n]);
    }
    for (int f = tid; f < 8192; f += 256) {
        int j = f & 7, lane = (f >> 3) & 63, nt = (f >> 9) & 7, ks = (f >> 12) & 1;
        int k = ks * 32 + ((lane >> 4) << 2) + (j & 3) + ((j & 4) << 2);
        int n = nt * 16 + (lane & 15);
        w1f[f] = f2bf(W1[k * 128 + n]);
    }
    __syncthreads();

    const int wv = tid >> 6;
    const int lane = tid & 63;
    const int lm = lane & 15;   // A-row / C-col index
    const int lq = lane >> 4;   // quarter

    float b0r[4], b1r[8];
#pragma unroll
    for (int nt = 0; nt < 4; ++nt) b0r[nt] = b0[nt * 16 + lm];
#pragma unroll
    for (int nt = 0; nt < 8; ++nt) b1r[nt] = b1[nt * 16 + lm];

    const bf16x8* w0v = (const bf16x8*)w0f;
    const bf16x8* w1v = (const bf16x8*)w1f;

    for (int t = 0; t < 4; ++t) {
        const int tile = (blockIdx.x * 4 + wv) * 4 + t;   // 0..49999
        const int ebase = tile * 16;

        // ---- A1 fragments straight from global (row = ebase+lm) ----
        const f32x4* er = (const f32x4*)(ef + (ebase + lm) * D_EDGE);
        f32x4 a0 = er[lq];      // k: lq*4 + 0..3
        f32x4 a1 = er[4 + lq];  // k: 16 + ...
        f32x4 a2 = er[8 + lq];  // k: 32 + ...
        f32x4 a3 = er[12 + lq]; // k: 48 + ...
        bf16x8 af0, af1;
#pragma unroll
        for (int j = 0; j < 4; ++j) {
            af0[j] = (short)f2bf(a0[j]); af0[j + 4] = (short)f2bf(a1[j]);
            af1[j] = (short)f2bf(a2[j]); af1[j + 4] = (short)f2bf(a3[j]);
        }

        // ---- layer 1: h[16x64] ----
        f32x4 h[4];
#pragma unroll
        for (int nt = 0; nt < 4; ++nt) { h[nt] = f32x4{0.f, 0.f, 0.f, 0.f}; }
#pragma unroll
        for (int nt = 0; nt < 4; ++nt) {
            h[nt] = __builtin_amdgcn_mfma_f32_16x16x32_bf16(af0, w0v[(0 * 4 + nt) * 64 + lane], h[nt], 0, 0, 0);
            h[nt] = __builtin_amdgcn_mfma_f32_16x16x32_bf16(af1, w0v[(1 * 4 + nt) * 64 + lane], h[nt], 0, 0, 0);
        }
        // bias + relu, transpose via LDS (D layout: row=lq*4+r, col=nt*16+lm)
#pragma unroll
        for (int nt = 0; nt < 4; ++nt)
#pragma unroll
            for (int r = 0; r < 4; ++r) {
                float x = h[nt][r] + b0r[nt];
                hT[wv][lq * 4 + r][nt * 16 + lm] = f2bf(fmaxf(x, 0.f));
            }

        // ---- A2 fragments from hT (row = lm) ----
        const unsigned short* hrow = &hT[wv][lm][0];
        u16x4 p0 = *(const u16x4*)(hrow + lq * 4);
        u16x4 p1 = *(const u16x4*)(hrow + 16 + lq * 4);
        u16x4 p2 = *(const u16x4*)(hrow + 32 + lq * 4);
        u16x4 p3 = *(const u16x4*)(hrow + 48 + lq * 4);
        bf16x8 g0, g1;
#pragma unroll
        for (int j = 0; j < 4; ++j) {
            g0[j] = (short)p0[j]; g0[j + 4] = (short)p1[j];
            g1[j] = (short)p2[j]; g1[j + 4] = (short)p3[j];
        }

        // ---- layer 2: e2[16x128] ----
        f32x4 o[8];
#pragma unroll
        for (int nt = 0; nt < 8; ++nt) { o[nt] = f32x4{0.f, 0.f, 0.f, 0.f}; }
#pragma unroll
        for (int nt = 0; nt < 8; ++nt) {
            o[nt] = __builtin_amdgcn_mfma_f32_16x16x32_bf16(g0, w1v[(0 * 8 + nt) * 64 + lane], o[nt], 0, 0, 0);
            o[nt] = __builtin_amdgcn_mfma_f32_16x16x32_bf16(g1, w1v[(1 * 8 + nt) * 64 + lane], o[nt], 0, 0, 0);
        }

        // ---- e = relu(o + b1); m = relu(node_feat[src] + e); scatter-add ----
        // NOTE: reference has TWO relus here; do not fuse them.
        const int e0 = ebase + lq * 4;
        int s_[4], d_[4];
#pragma unroll
        for (int r = 0; r < 4; ++r) { s_[r] = src[e0 + r]; d_[r] = dst[e0 + r]; }
#pragma unroll
        for (int r = 0; r < 4; ++r) {
            const float* nrow = nf + s_[r] * D_NODE;
            float* arow = acc + d_[r] * D_NODE;
#pragma unroll
            for (int nt = 0; nt < 8; ++nt) {
                float e2 = fmaxf(o[nt][r] + b1r[nt], 0.f);       // inner relu
                float x = e2 + nrow[nt * 16 + lm];
                unsafeAtomicAdd(&arow[nt * 16 + lm], fmaxf(x, 0.f));  // outer relu
            }
        }
    }
}

// ---------------- kernel 2: out = acc @ Wa + ba, in place ------
// acc already holds node_feat + neigh (= rst). Do NOT add node_feat again.
__global__ __launch_bounds__(256) void k_out(
    const float* __restrict__ Wa, const float* __restrict__ ba,
    float* __restrict__ out)
{
    __shared__ unsigned short waf[4 * 8 * 64 * 8];   // 32 KB

    const int tid = threadIdx.x;
    for (int f = tid; f < 16384; f += 256) {
        int j = f & 7, lane = (f >> 3) & 63, nt = (f >> 9) & 7, ks = (f >> 12) & 3;
        int k = ks * 32 + ((lane >> 4) << 2) + (j & 3) + ((j & 4) << 2);
        int n = nt * 16 + (lane & 15);
        waf[f] = f2bf(Wa[k * 128 + n]);
    }
    __syncthreads();

    const int wv = tid >> 6;
    const int lane = tid & 63;
    const int lm = lane & 15;
    const int lq = lane >> 4;

    const int tile = blockIdx.x * 4 + wv;
    if (tile >= N_NODES / 16) return;
    const int rbase = tile * 16;

    const f32x4* arow = (const f32x4*)(out + (rbase + lm) * D_NODE);
    const bf16x8* wav = (const bf16x8*)waf;

    bf16x8 afr[4];
#pragma unroll
    for (int ks = 0; ks < 4; ++ks) {
        f32x4 y0 = arow[ks * 8 + lq];
        f32x4 y1 = arow[ks * 8 + 4 + lq];
#pragma unroll
        for (int j = 0; j < 4; ++j) {
            afr[ks][j] = (short)f2bf(y0[j]);
            afr[ks][j + 4] = (short)f2bf(y1[j]);
        }
    }

    float bar[8];
#pragma unroll
    for (int nt = 0; nt < 8; ++nt) bar[nt] = ba[nt * 16 + lm];

    f32x4 o[8];
#pragma unroll
    for (int nt = 0; nt < 8; ++nt) { o[nt] = f32x4{0.f, 0.f, 0.f, 0.f}; }
#pragma unroll
    for (int ks = 0; ks < 4; ++ks)
#pragma unroll
        for (int nt = 0; nt < 8; ++nt)
            o[nt] = __builtin_amdgcn_mfma_f32_16x16x32_bf16(afr[ks], wav[(ks * 8 + nt) * 64 + lane], o[nt], 0, 0, 0);

#pragma unroll
    for (int nt = 0; nt < 8; ++nt)
#pragma unroll
        for (int r = 0; r < 4; ++r)
            out[(rbase + lq * 4 + r) * D_NODE + nt * 16 + lm] = o[nt][r] + bar[nt];
}

extern "C" void kernel_launch(void* const* d_in, const int* in_sizes, int n_in,
                              void* d_out, int out_size, void* d_ws, size_t ws_size,
                              hipStream_t stream) {
    const float* nf = (const float*)d_in[0];
    const float* ef = (const float*)d_in[1];
    const float* W0 = (const float*)d_in[2];
    const float* b0 = (const float*)d_in[3];
    const float* W1 = (const float*)d_in[4];
    const float* b1 = (const float*)d_in[5];
    const float* Wa = (const float*)d_in[6];
    const float* ba = (const float*)d_in[7];
    const int* src = (const int*)d_in[8];
    const int* dst = (const int*)d_in[9];
    float* out = (float*)d_out;

    // acc = node_feat
    k_copy<<<2048, 256, 0, stream>>>((const f32x4*)nf, (f32x4*)out, N_NODES * D_NODE / 4);
    // scatter messages into acc  (acc becomes rst = node_feat + neigh)
    k_edge<<<N_EDGES / (16 * 4 * 4), 256, 0, stream>>>(ef, nf, W0, b0, W1, b1, src, dst, out);
    // out = rst @ Wa + ba (in place)
    k_out<<<(N_NODES / 16 + 3) / 4, 256, 0, stream>>>(Wa, ba, out);
}

// Round 4
// 390.106 us; speedup vs baseline: 1.2002x; 1.2002x over previous
//
#include <hip/hip_runtime.h>

typedef short bf16x8 __attribute__((ext_vector_type(8)));
typedef float f32x4 __attribute__((ext_vector_type(4)));
typedef unsigned short u16x4 __attribute__((ext_vector_type(4)));
typedef unsigned short u16x8 __attribute__((ext_vector_type(8)));

static constexpr int N_NODES = 50000;
static constexpr int N_EDGES = 800000;
static constexpr int D_NODE = 128;
static constexpr int D_EDGE = 64;

// workspace layout (bytes)
static constexpr size_t START_OFF = 0;                       // (N_NODES+1) ints
static constexpr size_t FILL_OFF  = 262144;                  // N_NODES ints
static constexpr size_t POS_OFF   = 524288;                  // N_EDGES ints
static constexpr size_t MSG_OFF   = POS_OFF + (size_t)N_EDGES * 4;      // 3,724,288
static constexpr size_t WS_NEED   = MSG_OFF + (size_t)N_EDGES * D_NODE * 2;

__device__ __forceinline__ unsigned short f2bf(float f) {
    union { float f; unsigned u; } v; v.f = f;
    return (unsigned short)((v.u + 0x7fffu + ((v.u >> 16) & 1u)) >> 16);
}
__device__ __forceinline__ float bf2f(unsigned short h) {
    union { unsigned u; float f; } v; v.u = ((unsigned)h) << 16;
    return v.f;
}

// =============== preprocessing: CSR of edges by dst ==========================
__global__ void kz(int* __restrict__ a, int n) {
    int i = blockIdx.x * blockDim.x + threadIdx.x;
    if (i < n) a[i] = 0;
}

__global__ void kh(const int* __restrict__ dst, int* __restrict__ start) {
    int e = blockIdx.x * blockDim.x + threadIdx.x;
    if (e < N_EDGES) atomicAdd(&start[dst[e] + 1], 1);
}

// single-block inclusive scan over a[0..n-1] (n ~ 50001)
__global__ __launch_bounds__(1024) void kscan(int* __restrict__ a, int n) {
    __shared__ int sd[1024];
    __shared__ int carry;
    const int tid = threadIdx.x;
    if (tid == 0) carry = 0;
    __syncthreads();
    for (int base = 0; base < n; base += 1024) {
        int x = (base + tid < n) ? a[base + tid] : 0;
        sd[tid] = x; __syncthreads();
        for (int off = 1; off < 1024; off <<= 1) {
            int t = (tid >= off) ? sd[tid - off] : 0;
            __syncthreads();
            sd[tid] += t; __syncthreads();
        }
        int c = carry;
        if (base + tid < n) a[base + tid] = sd[tid] + c;
        __syncthreads();
        if (tid == 0) carry = c + sd[1023];
        __syncthreads();
    }
}

__global__ void kcopyfill(const int* __restrict__ start, int* __restrict__ fill, int n) {
    int i = blockIdx.x * blockDim.x + threadIdx.x;
    if (i < n) fill[i] = start[i];
}

__global__ void kpos(const int* __restrict__ dst, int* __restrict__ fill, int* __restrict__ pos) {
    int e = blockIdx.x * blockDim.x + threadIdx.x;
    if (e < N_EDGES) pos[e] = atomicAdd(&fill[dst[e]], 1);
}

// =============== phase 1: edge MLP -> bf16 message rows at CSR position ======
__global__ __launch_bounds__(256) void k_edge_msg(
    const float* __restrict__ ef, const float* __restrict__ nf,
    const float* __restrict__ W0, const float* __restrict__ b0,
    const float* __restrict__ W1, const float* __restrict__ b1,
    const int* __restrict__ src, const int* __restrict__ posp,
    unsigned short* __restrict__ msg)
{
    __shared__ unsigned short w0f[2 * 4 * 64 * 8];   // 8 KB
    __shared__ unsigned short w1f[2 * 8 * 64 * 8];   // 16 KB
    __shared__ unsigned short hT[4][16][72];         // layer-1 transpose
    __shared__ unsigned short mT[4][16][136];        // message tile (bf16), 16B-friendly stride

    const int tid = threadIdx.x;
    for (int f = tid; f < 4096; f += 256) {
        int j = f & 7, lane = (f >> 3) & 63, nt = (f >> 9) & 3, ks = (f >> 11) & 1;
        int k = ks * 32 + ((lane >> 4) << 2) + (j & 3) + ((j & 4) << 2);
        int n = nt * 16 + (lane & 15);
        w0f[f] = f2bf(W0[k * 64 + n]);
    }
    for (int f = tid; f < 8192; f += 256) {
        int j = f & 7, lane = (f >> 3) & 63, nt = (f >> 9) & 7, ks = (f >> 12) & 1;
        int k = ks * 32 + ((lane >> 4) << 2) + (j & 3) + ((j & 4) << 2);
        int n = nt * 16 + (lane & 15);
        w1f[f] = f2bf(W1[k * 128 + n]);
    }
    __syncthreads();

    const int wv = tid >> 6;
    const int lane = tid & 63;
    const int lm = lane & 15;
    const int lq = lane >> 4;

    float b0r[4], b1r[8];
#pragma unroll
    for (int nt = 0; nt < 4; ++nt) b0r[nt] = b0[nt * 16 + lm];
#pragma unroll
    for (int nt = 0; nt < 8; ++nt) b1r[nt] = b1[nt * 16 + lm];

    const bf16x8* w0v = (const bf16x8*)w0f;
    const bf16x8* w1v = (const bf16x8*)w1f;

    for (int t = 0; t < 4; ++t) {
        const int tile = (blockIdx.x * 4 + wv) * 4 + t;
        const int ebase = tile * 16;

        const f32x4* er = (const f32x4*)(ef + (size_t)(ebase + lm) * D_EDGE);
        f32x4 a0 = er[lq];
        f32x4 a1 = er[4 + lq];
        f32x4 a2 = er[8 + lq];
        f32x4 a3 = er[12 + lq];
        bf16x8 af0, af1;
#pragma unroll
        for (int j = 0; j < 4; ++j) {
            af0[j] = (short)f2bf(a0[j]); af0[j + 4] = (short)f2bf(a1[j]);
            af1[j] = (short)f2bf(a2[j]); af1[j + 4] = (short)f2bf(a3[j]);
        }

        // layer 1
        f32x4 h[4];
#pragma unroll
        for (int nt = 0; nt < 4; ++nt) h[nt] = f32x4{0.f, 0.f, 0.f, 0.f};
#pragma unroll
        for (int nt = 0; nt < 4; ++nt) {
            h[nt] = __builtin_amdgcn_mfma_f32_16x16x32_bf16(af0, w0v[(0 * 4 + nt) * 64 + lane], h[nt], 0, 0, 0);
            h[nt] = __builtin_amdgcn_mfma_f32_16x16x32_bf16(af1, w0v[(1 * 4 + nt) * 64 + lane], h[nt], 0, 0, 0);
        }
#pragma unroll
        for (int nt = 0; nt < 4; ++nt)
#pragma unroll
            for (int r = 0; r < 4; ++r) {
                float x = h[nt][r] + b0r[nt];
                hT[wv][lq * 4 + r][nt * 16 + lm] = f2bf(fmaxf(x, 0.f));
            }

        const unsigned short* hrow = &hT[wv][lm][0];
        u16x4 p0 = *(const u16x4*)(hrow + lq * 4);
        u16x4 p1 = *(const u16x4*)(hrow + 16 + lq * 4);
        u16x4 p2 = *(const u16x4*)(hrow + 32 + lq * 4);
        u16x4 p3 = *(const u16x4*)(hrow + 48 + lq * 4);
        bf16x8 g0, g1;
#pragma unroll
        for (int j = 0; j < 4; ++j) {
            g0[j] = (short)p0[j]; g0[j + 4] = (short)p1[j];
            g1[j] = (short)p2[j]; g1[j + 4] = (short)p3[j];
        }

        // layer 2
        f32x4 o[8];
#pragma unroll
        for (int nt = 0; nt < 8; ++nt) o[nt] = f32x4{0.f, 0.f, 0.f, 0.f};
#pragma unroll
        for (int nt = 0; nt < 8; ++nt) {
            o[nt] = __builtin_amdgcn_mfma_f32_16x16x32_bf16(g0, w1v[(0 * 8 + nt) * 64 + lane], o[nt], 0, 0, 0);
            o[nt] = __builtin_amdgcn_mfma_f32_16x16x32_bf16(g1, w1v[(1 * 8 + nt) * 64 + lane], o[nt], 0, 0, 0);
        }

        // e = relu(o + b1); m = relu(x_src + e) -> bf16 tile in LDS
        const int e0 = ebase + lq * 4;
        int s_[4];
#pragma unroll
        for (int r = 0; r < 4; ++r) s_[r] = src[e0 + r];
#pragma unroll
        for (int r = 0; r < 4; ++r) {
            const float* nrow = nf + (size_t)s_[r] * D_NODE;
#pragma unroll
            for (int nt = 0; nt < 8; ++nt) {
                float e2 = fmaxf(o[nt][r] + b1r[nt], 0.f);
                float x = e2 + nrow[nt * 16 + lm];
                mT[wv][lq * 4 + r][nt * 16 + lm] = f2bf(fmaxf(x, 0.f));
            }
        }

        // cooperative row stores: quarter lq writes rows p*4+lq, 16 lanes x 16B
#pragma unroll
        for (int p = 0; p < 4; ++p) {
            const int row = p * 4 + lq;
            const int prow = posp[ebase + row];
            u16x8 v = *(const u16x8*)&mT[wv][row][lm * 8];
            *(u16x8*)(msg + (size_t)prow * D_NODE + lm * 8) = v;
        }
    }
}

// =============== phase 2: rst[v] = nf[v] + sum(msg rows of v) ================
// one 16-lane quarter per node
__global__ __launch_bounds__(256) void k_reduce(
    const float* __restrict__ nf, const unsigned short* __restrict__ msg,
    const int* __restrict__ start, float* __restrict__ out)
{
    const int tid = threadIdx.x;
    const int li = tid & 15;
    const int v = blockIdx.x * 16 + (tid >> 4);
    if (v >= N_NODES) return;

    const int s = start[v];
    const int e = start[v + 1];

    const f32x4* nrow = (const f32x4*)(nf + (size_t)v * D_NODE);
    f32x4 acc0 = nrow[li * 2];
    f32x4 acc1 = nrow[li * 2 + 1];

    for (int i = s; i < e; ++i) {
        u16x8 m = *(const u16x8*)(msg + (size_t)i * D_NODE + li * 8);
#pragma unroll
        for (int j = 0; j < 4; ++j) acc0[j] += bf2f(m[j]);
#pragma unroll
        for (int j = 0; j < 4; ++j) acc1[j] += bf2f(m[4 + j]);
    }

    f32x4* orow = (f32x4*)(out + (size_t)v * D_NODE);
    orow[li * 2] = acc0;
    orow[li * 2 + 1] = acc1;
}

// =============== fallback path (atomic scatter), known-good ==================
__global__ void k_copy(const f32x4* __restrict__ s, f32x4* __restrict__ d, int n4) {
    int stride = gridDim.x * blockDim.x;
    for (int i = blockIdx.x * blockDim.x + threadIdx.x; i < n4; i += stride)
        d[i] = s[i];
}

__global__ __launch_bounds__(256) void k_edge(
    const float* __restrict__ ef, const float* __restrict__ nf,
    const float* __restrict__ W0, const float* __restrict__ b0,
    const float* __restrict__ W1, const float* __restrict__ b1,
    const int* __restrict__ src, const int* __restrict__ dst,
    float* __restrict__ acc)
{
    __shared__ unsigned short w0f[2 * 4 * 64 * 8];
    __shared__ unsigned short w1f[2 * 8 * 64 * 8];
    __shared__ unsigned short hT[4][16][72];

    const int tid = threadIdx.x;
    for (int f = tid; f < 4096; f += 256) {
        int j = f & 7, lane = (f >> 3) & 63, nt = (f >> 9) & 3, ks = (f >> 11) & 1;
        int k = ks * 32 + ((lane >> 4) << 2) + (j & 3) + ((j & 4) << 2);
        int n = nt * 16 + (lane & 15);
        w0f[f] = f2bf(W0[k * 64 + n]);
    }
    for (int f = tid; f < 8192; f += 256) {
        int j = f & 7, lane = (f >> 3) & 63, nt = (f >> 9) & 7, ks = (f >> 12) & 1;
        int k = ks * 32 + ((lane >> 4) << 2) + (j & 3) + ((j & 4) << 2);
        int n = nt * 16 + (lane & 15);
        w1f[f] = f2bf(W1[k * 128 + n]);
    }
    __syncthreads();

    const int wv = tid >> 6;
    const int lane = tid & 63;
    const int lm = lane & 15;
    const int lq = lane >> 4;

    float b0r[4], b1r[8];
#pragma unroll
    for (int nt = 0; nt < 4; ++nt) b0r[nt] = b0[nt * 16 + lm];
#pragma unroll
    for (int nt = 0; nt < 8; ++nt) b1r[nt] = b1[nt * 16 + lm];

    const bf16x8* w0v = (const bf16x8*)w0f;
    const bf16x8* w1v = (const bf16x8*)w1f;

    for (int t = 0; t < 4; ++t) {
        const int tile = (blockIdx.x * 4 + wv) * 4 + t;
        const int ebase = tile * 16;

        const f32x4* er = (const f32x4*)(ef + (size_t)(ebase + lm) * D_EDGE);
        f32x4 a0 = er[lq];
        f32x4 a1 = er[4 + lq];
        f32x4 a2 = er[8 + lq];
        f32x4 a3 = er[12 + lq];
        bf16x8 af0, af1;
#pragma unroll
        for (int j = 0; j < 4; ++j) {
            af0[j] = (short)f2bf(a0[j]); af0[j + 4] = (short)f2bf(a1[j]);
            af1[j] = (short)f2bf(a2[j]); af1[j + 4] = (short)f2bf(a3[j]);
        }

        f32x4 h[4];
#pragma unroll
        for (int nt = 0; nt < 4; ++nt) h[nt] = f32x4{0.f, 0.f, 0.f, 0.f};
#pragma unroll
        for (int nt = 0; nt < 4; ++nt) {
            h[nt] = __builtin_amdgcn_mfma_f32_16x16x32_bf16(af0, w0v[(0 * 4 + nt) * 64 + lane], h[nt], 0, 0, 0);
            h[nt] = __builtin_amdgcn_mfma_f32_16x16x32_bf16(af1, w0v[(1 * 4 + nt) * 64 + lane], h[nt], 0, 0, 0);
        }
#pragma unroll
        for (int nt = 0; nt < 4; ++nt)
#pragma unroll
            for (int r = 0; r < 4; ++r) {
                float x = h[nt][r] + b0r[nt];
                hT[wv][lq * 4 + r][nt * 16 + lm] = f2bf(fmaxf(x, 0.f));
            }

        const unsigned short* hrow = &hT[wv][lm][0];
        u16x4 p0 = *(const u16x4*)(hrow + lq * 4);
        u16x4 p1 = *(const u16x4*)(hrow + 16 + lq * 4);
        u16x4 p2 = *(const u16x4*)(hrow + 32 + lq * 4);
        u16x4 p3 = *(const u16x4*)(hrow + 48 + lq * 4);
        bf16x8 g0, g1;
#pragma unroll
        for (int j = 0; j < 4; ++j) {
            g0[j] = (short)p0[j]; g0[j + 4] = (short)p1[j];
            g1[j] = (short)p2[j]; g1[j + 4] = (short)p3[j];
        }

        f32x4 o[8];
#pragma unroll
        for (int nt = 0; nt < 8; ++nt) o[nt] = f32x4{0.f, 0.f, 0.f, 0.f};
#pragma unroll
        for (int nt = 0; nt < 8; ++nt) {
            o[nt] = __builtin_amdgcn_mfma_f32_16x16x32_bf16(g0, w1v[(0 * 8 + nt) * 64 + lane], o[nt], 0, 0, 0);
            o[nt] = __builtin_amdgcn_mfma_f32_16x16x32_bf16(g1, w1v[(1 * 8 + nt) * 64 + lane], o[nt], 0, 0, 0);
        }

        const int e0 = ebase + lq * 4;
        int s_[4], d_[4];
#pragma unroll
        for (int r = 0; r < 4; ++r) { s_[r] = src[e0 + r]; d_[r] = dst[e0 + r]; }
#pragma unroll
        for (int r = 0; r < 4; ++r) {
            const float* nrow = nf + (size_t)s_[r] * D_NODE;
            float* arow = acc + (size_t)d_[r] * D_NODE;
#pragma unroll
            for (int nt = 0; nt < 8; ++nt) {
                float e2 = fmaxf(o[nt][r] + b1r[nt], 0.f);
                float x = e2 + nrow[nt * 16 + lm];
                unsafeAtomicAdd(&arow[nt * 16 + lm], fmaxf(x, 0.f));
            }
        }
    }
}

// =============== kernel: out = acc @ Wa + ba, in place =======================
__global__ __launch_bounds__(256) void k_out(
    const float* __restrict__ Wa, const float* __restrict__ ba,
    float* __restrict__ out)
{
    __shared__ unsigned short waf[4 * 8 * 64 * 8];   // 32 KB

    const int tid = threadIdx.x;
    for (int f = tid; f < 16384; f += 256) {
        int j = f & 7, lane = (f >> 3) & 63, nt = (f >> 9) & 7, ks = (f >> 12) & 3;
        int k = ks * 32 + ((lane >> 4) << 2) + (j & 3) + ((j & 4) << 2);
        int n = nt * 16 + (lane & 15);
        waf[f] = f2bf(Wa[k * 128 + n]);
    }
    __syncthreads();

    const int wv = tid >> 6;
    const int lane = tid & 63;
    const int lm = lane & 15;
    const int lq = lane >> 4;

    const int tile = blockIdx.x * 4 + wv;
    if (tile >= N_NODES / 16) return;
    const int rbase = tile * 16;

    const f32x4* arow = (const f32x4*)(out + (size_t)(rbase + lm) * D_NODE);
    const bf16x8* wav = (const bf16x8*)waf;

    bf16x8 afr[4];
#pragma unroll
    for (int ks = 0; ks < 4; ++ks) {
        f32x4 y0 = arow[ks * 8 + lq];
        f32x4 y1 = arow[ks * 8 + 4 + lq];
#pragma unroll
        for (int j = 0; j < 4; ++j) {
            afr[ks][j] = (short)f2bf(y0[j]);
            afr[ks][j + 4] = (short)f2bf(y1[j]);
        }
    }

    float bar[8];
#pragma unroll
    for (int nt = 0; nt < 8; ++nt) bar[nt] = ba[nt * 16 + lm];

    f32x4 o[8];
#pragma unroll
    for (int nt = 0; nt < 8; ++nt) o[nt] = f32x4{0.f, 0.f, 0.f, 0.f};
#pragma unroll
    for (int ks = 0; ks < 4; ++ks)
#pragma unroll
        for (int nt = 0; nt < 8; ++nt)
            o[nt] = __builtin_amdgcn_mfma_f32_16x16x32_bf16(afr[ks], wav[(ks * 8 + nt) * 64 + lane], o[nt], 0, 0, 0);

#pragma unroll
    for (int nt = 0; nt < 8; ++nt)
#pragma unroll
        for (int r = 0; r < 4; ++r)
            out[(size_t)(rbase + lq * 4 + r) * D_NODE + nt * 16 + lm] = o[nt][r] + bar[nt];
}

extern "C" void kernel_launch(void* const* d_in, const int* in_sizes, int n_in,
                              void* d_out, int out_size, void* d_ws, size_t ws_size,
                              hipStream_t stream) {
    const float* nf = (const float*)d_in[0];
    const float* ef = (const float*)d_in[1];
    const float* W0 = (const float*)d_in[2];
    const float* b0 = (const float*)d_in[3];
    const float* W1 = (const float*)d_in[4];
    const float* b1 = (const float*)d_in[5];
    const float* Wa = (const float*)d_in[6];
    const float* ba = (const float*)d_in[7];
    const int* src = (const int*)d_in[8];
    const int* dst = (const int*)d_in[9];
    float* out = (float*)d_out;

    if (ws_size >= WS_NEED) {
        char* ws = (char*)d_ws;
        int* start = (int*)(ws + START_OFF);
        int* fill  = (int*)(ws + FILL_OFF);
        int* pos   = (int*)(ws + POS_OFF);
        unsigned short* msg = (unsigned short*)(ws + MSG_OFF);

        // CSR build
        kz<<<(N_NODES + 1 + 255) / 256, 256, 0, stream>>>(start, N_NODES + 1);
        kh<<<(N_EDGES + 255) / 256, 256, 0, stream>>>(dst, start);
        kscan<<<1, 1024, 0, stream>>>(start, N_NODES + 1);
        kcopyfill<<<(N_NODES + 255) / 256, 256, 0, stream>>>(start, fill, N_NODES);
        kpos<<<(N_EDGES + 255) / 256, 256, 0, stream>>>(dst, fill, pos);

        // phase 1: messages -> msgbuf (bf16, CSR order), no atomics
        k_edge_msg<<<N_EDGES / (16 * 4 * 4), 256, 0, stream>>>(
            ef, nf, W0, b0, W1, b1, src, pos, msg);
        // phase 2: rst = nf + segment-sum(msg) -> d_out
        k_reduce<<<(N_NODES + 15) / 16, 256, 0, stream>>>(nf, msg, start, out);
    } else {
        // fallback: atomic scatter path
        k_copy<<<2048, 256, 0, stream>>>((const f32x4*)nf, (f32x4*)out, N_NODES * D_NODE / 4);
        k_edge<<<N_EDGES / (16 * 4 * 4), 256, 0, stream>>>(ef, nf, W0, b0, W1, b1, src, dst, out);
    }

    // out = rst @ Wa + ba (in place)
    k_out<<<(N_NODES / 16 + 3) / 4, 256, 0, stream>>>(Wa, ba, out);
}

// Round 5
// 342.015 us; speedup vs baseline: 1.3690x; 1.1406x over previous
//
#include <hip/hip_runtime.h>

typedef short bf16x8 __attribute__((ext_vector_type(8)));
typedef float f32x4 __attribute__((ext_vector_type(4)));
typedef unsigned short u16x4 __attribute__((ext_vector_type(4)));
typedef unsigned short u16x8 __attribute__((ext_vector_type(8)));

static constexpr int N_NODES = 50000;
static constexpr int N_EDGES = 800000;
static constexpr int D_NODE = 128;
static constexpr int D_EDGE = 64;

// workspace layout (bytes)
static constexpr size_t START_OFF = 0;                       // (N_NODES+1) ints
static constexpr size_t FILL_OFF  = 262144;                  // N_NODES ints
static constexpr size_t POS_OFF   = 524288;                  // N_EDGES ints (also bsum scratch)
static constexpr size_t MSG_OFF   = POS_OFF + (size_t)N_EDGES * 4;
static constexpr size_t WS_NEED   = MSG_OFF + (size_t)N_EDGES * D_NODE * 2;

__device__ __forceinline__ unsigned short f2bf(float f) {
    union { float f; unsigned u; } v; v.f = f;
    return (unsigned short)((v.u + 0x7fffu + ((v.u >> 16) & 1u)) >> 16);
}
__device__ __forceinline__ float bf2f(unsigned short h) {
    union { unsigned u; float f; } v; v.u = ((unsigned)h) << 16;
    return v.f;
}

// =============== preprocessing: CSR of edges by dst ==========================
__global__ void kz(int* __restrict__ a, int n) {
    int i = blockIdx.x * blockDim.x + threadIdx.x;
    if (i < n) a[i] = 0;
}

__global__ void kh(const int* __restrict__ dst, int* __restrict__ start) {
    int e = blockIdx.x * blockDim.x + threadIdx.x;
    if (e < N_EDGES) atomicAdd(&start[dst[e] + 1], 1);
}

// hierarchical scan over start[0..n-1], n = N_NODES+1, 256-elem blocks
__global__ __launch_bounds__(256) void ks1(const int* __restrict__ a, int* __restrict__ bsum, int n) {
    __shared__ int sd[256];
    const int t = threadIdx.x;
    int i = blockIdx.x * 256 + t;
    sd[t] = (i < n) ? a[i] : 0;
    __syncthreads();
    for (int off = 128; off > 0; off >>= 1) {
        if (t < off) sd[t] += sd[t + off];
        __syncthreads();
    }
    if (t == 0) bsum[blockIdx.x] = sd[0];
}

__global__ __launch_bounds__(256) void ks2(int* __restrict__ bsum, int nb) {
    __shared__ int sd[256];
    const int t = threadIdx.x;
    sd[t] = (t < nb) ? bsum[t] : 0;
    __syncthreads();
    for (int off = 1; off < 256; off <<= 1) {
        int v = (t >= off) ? sd[t - off] : 0;
        __syncthreads();
        sd[t] += v;
        __syncthreads();
    }
    if (t < nb) bsum[t] = sd[t];
}

__global__ __launch_bounds__(256) void ks3(const int* __restrict__ bsum,
                                           int* __restrict__ start, int* __restrict__ fill, int n) {
    __shared__ int sd[256];
    const int t = threadIdx.x;
    const int i = blockIdx.x * 256 + t;
    sd[t] = (i < n) ? start[i] : 0;
    __syncthreads();
    for (int off = 1; off < 256; off <<= 1) {
        int v = (t >= off) ? sd[t - off] : 0;
        __syncthreads();
        sd[t] += v;
        __syncthreads();
    }
    const int off0 = (blockIdx.x > 0) ? bsum[blockIdx.x - 1] : 0;
    const int val = sd[t] + off0;
    if (i < n) start[i] = val;
    if (i < N_NODES) fill[i] = val;
}

__global__ void kpos(const int* __restrict__ dst, int* __restrict__ fill, int* __restrict__ pos) {
    int e = blockIdx.x * blockDim.x + threadIdx.x;
    if (e < N_EDGES) pos[e] = atomicAdd(&fill[dst[e]], 1);
}

// =============== phase 1: edge MLP -> bf16 message rows at CSR position ======
// 512 threads = 8 waves sharing one weight copy; 2 tiles of 16 edges per wave.
__global__ __launch_bounds__(512) void k_edge_msg(
    const float* __restrict__ ef, const float* __restrict__ nf,
    const float* __restrict__ W0, const float* __restrict__ b0,
    const float* __restrict__ W1, const float* __restrict__ b1,
    const int* __restrict__ src, const int* __restrict__ posp,
    unsigned short* __restrict__ msg)
{
    __shared__ unsigned short w0f[2 * 4 * 64 * 8];   // 8 KB
    __shared__ unsigned short w1f[2 * 8 * 64 * 8];   // 16 KB
    __shared__ unsigned short hT[8][16][72];         // layer-1 transpose
    __shared__ unsigned short eT[8][16][136];        // e = relu(h@W1+b1) tile

    const int tid = threadIdx.x;
    for (int f = tid; f < 4096; f += 512) {
        int j = f & 7, lane = (f >> 3) & 63, nt = (f >> 9) & 3, ks = (f >> 11) & 1;
        int k = ks * 32 + ((lane >> 4) << 2) + (j & 3) + ((j & 4) << 2);
        int n = nt * 16 + (lane & 15);
        w0f[f] = f2bf(W0[k * 64 + n]);
    }
    for (int f = tid; f < 8192; f += 512) {
        int j = f & 7, lane = (f >> 3) & 63, nt = (f >> 9) & 7, ks = (f >> 12) & 1;
        int k = ks * 32 + ((lane >> 4) << 2) + (j & 3) + ((j & 4) << 2);
        int n = nt * 16 + (lane & 15);
        w1f[f] = f2bf(W1[k * 128 + n]);
    }
    __syncthreads();

    const int wv = tid >> 6;
    const int lane = tid & 63;
    const int lm = lane & 15;
    const int lq = lane >> 4;

    float b0r[4], b1r[8];
#pragma unroll
    for (int nt = 0; nt < 4; ++nt) b0r[nt] = b0[nt * 16 + lm];
#pragma unroll
    for (int nt = 0; nt < 8; ++nt) b1r[nt] = b1[nt * 16 + lm];

    const bf16x8* w0v = (const bf16x8*)w0f;
    const bf16x8* w1v = (const bf16x8*)w1f;

    for (int t = 0; t < 2; ++t) {
        const int tile = (blockIdx.x * 8 + wv) * 2 + t;   // 0..49999
        const int ebase = tile * 16;

        const f32x4* er = (const f32x4*)(ef + (size_t)(ebase + lm) * D_EDGE);
        f32x4 a0 = er[lq];
        f32x4 a1 = er[4 + lq];
        f32x4 a2 = er[8 + lq];
        f32x4 a3 = er[12 + lq];
        bf16x8 af0, af1;
#pragma unroll
        for (int j = 0; j < 4; ++j) {
            af0[j] = (short)f2bf(a0[j]); af0[j + 4] = (short)f2bf(a1[j]);
            af1[j] = (short)f2bf(a2[j]); af1[j + 4] = (short)f2bf(a3[j]);
        }

        // layer 1
        f32x4 h[4];
#pragma unroll
        for (int nt = 0; nt < 4; ++nt) h[nt] = f32x4{0.f, 0.f, 0.f, 0.f};
#pragma unroll
        for (int nt = 0; nt < 4; ++nt) {
            h[nt] = __builtin_amdgcn_mfma_f32_16x16x32_bf16(af0, w0v[(0 * 4 + nt) * 64 + lane], h[nt], 0, 0, 0);
            h[nt] = __builtin_amdgcn_mfma_f32_16x16x32_bf16(af1, w0v[(1 * 4 + nt) * 64 + lane], h[nt], 0, 0, 0);
        }
#pragma unroll
        for (int nt = 0; nt < 4; ++nt)
#pragma unroll
            for (int r = 0; r < 4; ++r) {
                float x = h[nt][r] + b0r[nt];
                hT[wv][lq * 4 + r][nt * 16 + lm] = f2bf(fmaxf(x, 0.f));
            }

        const unsigned short* hrow = &hT[wv][lm][0];
        u16x4 p0 = *(const u16x4*)(hrow + lq * 4);
        u16x4 p1 = *(const u16x4*)(hrow + 16 + lq * 4);
        u16x4 p2 = *(const u16x4*)(hrow + 32 + lq * 4);
        u16x4 p3 = *(const u16x4*)(hrow + 48 + lq * 4);
        bf16x8 g0, g1;
#pragma unroll
        for (int j = 0; j < 4; ++j) {
            g0[j] = (short)p0[j]; g0[j + 4] = (short)p1[j];
            g1[j] = (short)p2[j]; g1[j + 4] = (short)p3[j];
        }

        // layer 2
        f32x4 o[8];
#pragma unroll
        for (int nt = 0; nt < 8; ++nt) o[nt] = f32x4{0.f, 0.f, 0.f, 0.f};
#pragma unroll
        for (int nt = 0; nt < 8; ++nt) {
            o[nt] = __builtin_amdgcn_mfma_f32_16x16x32_bf16(g0, w1v[(0 * 8 + nt) * 64 + lane], o[nt], 0, 0, 0);
            o[nt] = __builtin_amdgcn_mfma_f32_16x16x32_bf16(g1, w1v[(1 * 8 + nt) * 64 + lane], o[nt], 0, 0, 0);
        }

        // e = relu(o + b1) -> LDS tile (bf16)
#pragma unroll
        for (int nt = 0; nt < 8; ++nt)
#pragma unroll
            for (int r = 0; r < 4; ++r)
                eT[wv][lq * 4 + r][nt * 16 + lm] = f2bf(fmaxf(o[nt][r] + b1r[nt], 0.f));

        // per row (quarter lq handles rows p*4+lq):
        // m = relu(nf[src] + e), vectorized row gather, single coalesced store
#pragma unroll
        for (int p = 0; p < 4; ++p) {
            const int row = p * 4 + lq;
            const int srow = src[ebase + row];
            const int prow = posp[ebase + row];
            u16x8 ev = *(const u16x8*)&eT[wv][row][lm * 8];
            const f32x4* nrow = (const f32x4*)(nf + (size_t)srow * D_NODE + lm * 8);
            f32x4 n0 = nrow[0];
            f32x4 n1 = nrow[1];
            u16x8 m;
#pragma unroll
            for (int j = 0; j < 4; ++j) m[j] = f2bf(fmaxf(n0[j] + bf2f(ev[j]), 0.f));
#pragma unroll
            for (int j = 0; j < 4; ++j) m[4 + j] = f2bf(fmaxf(n1[j] + bf2f(ev[4 + j]), 0.f));
            *(u16x8*)(msg + (size_t)prow * D_NODE + lm * 8) = m;
        }
    }
}

// =============== phase 2: rst[v] = nf[v] + sum(msg rows of v) ================
// one full wave per node: quarter lq streams rows s+lq, s+lq+4, ...
__global__ __launch_bounds__(256) void k_reduce(
    const float* __restrict__ nf, const unsigned short* __restrict__ msg,
    const int* __restrict__ start, float* __restrict__ out)
{
    const int tid = threadIdx.x;
    const int wv = tid >> 6;
    const int lane = tid & 63;
    const int lq = lane >> 4;
    const int li = lane & 15;
    const int v = blockIdx.x * 4 + wv;
    if (v >= N_NODES) return;

    const int s = start[v];
    const int e = start[v + 1];

    f32x4 acc0 = f32x4{0.f, 0.f, 0.f, 0.f};
    f32x4 acc1 = f32x4{0.f, 0.f, 0.f, 0.f};

    for (int i = s + lq; i < e; i += 4) {
        u16x8 m = *(const u16x8*)(msg + (size_t)i * D_NODE + li * 8);
#pragma unroll
        for (int j = 0; j < 4; ++j) acc0[j] += bf2f(m[j]);
#pragma unroll
        for (int j = 0; j < 4; ++j) acc1[j] += bf2f(m[4 + j]);
    }

    // cross-quarter reduce (lanes lq*16+li, same li share columns)
#pragma unroll
    for (int j = 0; j < 4; ++j) {
        acc0[j] += __shfl_xor(acc0[j], 16);
        acc0[j] += __shfl_xor(acc0[j], 32);
        acc1[j] += __shfl_xor(acc1[j], 16);
        acc1[j] += __shfl_xor(acc1[j], 32);
    }

    if (lq == 0) {
        const f32x4* nrow = (const f32x4*)(nf + (size_t)v * D_NODE);
        f32x4* orow = (f32x4*)(out + (size_t)v * D_NODE);
        orow[li * 2] = nrow[li * 2] + acc0;
        orow[li * 2 + 1] = nrow[li * 2 + 1] + acc1;
    }
}

// =============== fallback path (atomic scatter), known-good ==================
__global__ void k_copy(const f32x4* __restrict__ s, f32x4* __restrict__ d, int n4) {
    int stride = gridDim.x * blockDim.x;
    for (int i = blockIdx.x * blockDim.x + threadIdx.x; i < n4; i += stride)
        d[i] = s[i];
}

__global__ __launch_bounds__(256) void k_edge(
    const float* __restrict__ ef, const float* __restrict__ nf,
    const float* __restrict__ W0, const float* __restrict__ b0,
    const float* __restrict__ W1, const float* __restrict__ b1,
    const int* __restrict__ src, const int* __restrict__ dst,
    float* __restrict__ acc)
{
    __shared__ unsigned short w0f[2 * 4 * 64 * 8];
    __shared__ unsigned short w1f[2 * 8 * 64 * 8];
    __shared__ unsigned short hT[4][16][72];

    const int tid = threadIdx.x;
    for (int f = tid; f < 4096; f += 256) {
        int j = f & 7, lane = (f >> 3) & 63, nt = (f >> 9) & 3, ks = (f >> 11) & 1;
        int k = ks * 32 + ((lane >> 4) << 2) + (j & 3) + ((j & 4) << 2);
        int n = nt * 16 + (lane & 15);
        w0f[f] = f2bf(W0[k * 64 + n]);
    }
    for (int f = tid; f < 8192; f += 256) {
        int j = f & 7, lane = (f >> 3) & 63, nt = (f >> 9) & 7, ks = (f >> 12) & 1;
        int k = ks * 32 + ((lane >> 4) << 2) + (j & 3) + ((j & 4) << 2);
        int n = nt * 16 + (lane & 15);
        w1f[f] = f2bf(W1[k * 128 + n]);
    }
    __syncthreads();

    const int wv = tid >> 6;
    const int lane = tid & 63;
    const int lm = lane & 15;
    const int lq = lane >> 4;

    float b0r[4], b1r[8];
#pragma unroll
    for (int nt = 0; nt < 4; ++nt) b0r[nt] = b0[nt * 16 + lm];
#pragma unroll
    for (int nt = 0; nt < 8; ++nt) b1r[nt] = b1[nt * 16 + lm];

    const bf16x8* w0v = (const bf16x8*)w0f;
    const bf16x8* w1v = (const bf16x8*)w1f;

    for (int t = 0; t < 4; ++t) {
        const int tile = (blockIdx.x * 4 + wv) * 4 + t;
        const int ebase = tile * 16;

        const f32x4* er = (const f32x4*)(ef + (size_t)(ebase + lm) * D_EDGE);
        f32x4 a0 = er[lq];
        f32x4 a1 = er[4 + lq];
        f32x4 a2 = er[8 + lq];
        f32x4 a3 = er[12 + lq];
        bf16x8 af0, af1;
#pragma unroll
        for (int j = 0; j < 4; ++j) {
            af0[j] = (short)f2bf(a0[j]); af0[j + 4] = (short)f2bf(a1[j]);
            af1[j] = (short)f2bf(a2[j]); af1[j + 4] = (short)f2bf(a3[j]);
        }

        f32x4 h[4];
#pragma unroll
        for (int nt = 0; nt < 4; ++nt) h[nt] = f32x4{0.f, 0.f, 0.f, 0.f};
#pragma unroll
        for (int nt = 0; nt < 4; ++nt) {
            h[nt] = __builtin_amdgcn_mfma_f32_16x16x32_bf16(af0, w0v[(0 * 4 + nt) * 64 + lane], h[nt], 0, 0, 0);
            h[nt] = __builtin_amdgcn_mfma_f32_16x16x32_bf16(af1, w0v[(1 * 4 + nt) * 64 + lane], h[nt], 0, 0, 0);
        }
#pragma unroll
        for (int nt = 0; nt < 4; ++nt)
#pragma unroll
            for (int r = 0; r < 4; ++r) {
                float x = h[nt][r] + b0r[nt];
                hT[wv][lq * 4 + r][nt * 16 + lm] = f2bf(fmaxf(x, 0.f));
            }

        const unsigned short* hrow = &hT[wv][lm][0];
        u16x4 p0 = *(const u16x4*)(hrow + lq * 4);
        u16x4 p1 = *(const u16x4*)(hrow + 16 + lq * 4);
        u16x4 p2 = *(const u16x4*)(hrow + 32 + lq * 4);
        u16x4 p3 = *(const u16x4*)(hrow + 48 + lq * 4);
        bf16x8 g0, g1;
#pragma unroll
        for (int j = 0; j < 4; ++j) {
            g0[j] = (short)p0[j]; g0[j + 4] = (short)p1[j];
            g1[j] = (short)p2[j]; g1[j + 4] = (short)p3[j];
        }

        f32x4 o[8];
#pragma unroll
        for (int nt = 0; nt < 8; ++nt) o[nt] = f32x4{0.f, 0.f, 0.f, 0.f};
#pragma unroll
        for (int nt = 0; nt < 8; ++nt) {
            o[nt] = __builtin_amdgcn_mfma_f32_16x16x32_bf16(g0, w1v[(0 * 8 + nt) * 64 + lane], o[nt], 0, 0, 0);
            o[nt] = __builtin_amdgcn_mfma_f32_16x16x32_bf16(g1, w1v[(1 * 8 + nt) * 64 + lane], o[nt], 0, 0, 0);
        }

        const int e0 = ebase + lq * 4;
        int s_[4], d_[4];
#pragma unroll
        for (int r = 0; r < 4; ++r) { s_[r] = src[e0 + r]; d_[r] = dst[e0 + r]; }
#pragma unroll
        for (int r = 0; r < 4; ++r) {
            const float* nrow = nf + (size_t)s_[r] * D_NODE;
            float* arow = acc + (size_t)d_[r] * D_NODE;
#pragma unroll
            for (int nt = 0; nt < 8; ++nt) {
                float e2 = fmaxf(o[nt][r] + b1r[nt], 0.f);
                float x = e2 + nrow[nt * 16 + lm];
                unsafeAtomicAdd(&arow[nt * 16 + lm], fmaxf(x, 0.f));
            }
        }
    }
}

// =============== kernel: out = acc @ Wa + ba, in place =======================
__global__ __launch_bounds__(256) void k_out(
    const float* __restrict__ Wa, const float* __restrict__ ba,
    float* __restrict__ out)
{
    __shared__ unsigned short waf[4 * 8 * 64 * 8];   // 32 KB

    const int tid = threadIdx.x;
    for (int f = tid; f < 16384; f += 256) {
        int j = f & 7, lane = (f >> 3) & 63, nt = (f >> 9) & 7, ks = (f >> 12) & 3;
        int k = ks * 32 + ((lane >> 4) << 2) + (j & 3) + ((j & 4) << 2);
        int n = nt * 16 + (lane & 15);
        waf[f] = f2bf(Wa[k * 128 + n]);
    }
    __syncthreads();

    const int wv = tid >> 6;
    const int lane = tid & 63;
    const int lm = lane & 15;
    const int lq = lane >> 4;

    const int tile = blockIdx.x * 4 + wv;
    if (tile >= N_NODES / 16) return;
    const int rbase = tile * 16;

    const f32x4* arow = (const f32x4*)(out + (size_t)(rbase + lm) * D_NODE);
    const bf16x8* wav = (const bf16x8*)waf;

    bf16x8 afr[4];
#pragma unroll
    for (int ks = 0; ks < 4; ++ks) {
        f32x4 y0 = arow[ks * 8 + lq];
        f32x4 y1 = arow[ks * 8 + 4 + lq];
#pragma unroll
        for (int j = 0; j < 4; ++j) {
            afr[ks][j] = (short)f2bf(y0[j]);
            afr[ks][j + 4] = (short)f2bf(y1[j]);
        }
    }

    float bar[8];
#pragma unroll
    for (int nt = 0; nt < 8; ++nt) bar[nt] = ba[nt * 16 + lm];

    f32x4 o[8];
#pragma unroll
    for (int nt = 0; nt < 8; ++nt) o[nt] = f32x4{0.f, 0.f, 0.f, 0.f};
#pragma unroll
    for (int ks = 0; ks < 4; ++ks)
#pragma unroll
        for (int nt = 0; nt < 8; ++nt)
            o[nt] = __builtin_amdgcn_mfma_f32_16x16x32_bf16(afr[ks], wav[(ks * 8 + nt) * 64 + lane], o[nt], 0, 0, 0);

#pragma unroll
    for (int nt = 0; nt < 8; ++nt)
#pragma unroll
        for (int r = 0; r < 4; ++r)
            out[(size_t)(rbase + lq * 4 + r) * D_NODE + nt * 16 + lm] = o[nt][r] + bar[nt];
}

extern "C" void kernel_launch(void* const* d_in, const int* in_sizes, int n_in,
                              void* d_out, int out_size, void* d_ws, size_t ws_size,
                              hipStream_t stream) {
    const float* nf = (const float*)d_in[0];
    const float* ef = (const float*)d_in[1];
    const float* W0 = (const float*)d_in[2];
    const float* b0 = (const float*)d_in[3];
    const float* W1 = (const float*)d_in[4];
    const float* b1 = (const float*)d_in[5];
    const float* Wa = (const float*)d_in[6];
    const float* ba = (const float*)d_in[7];
    const int* src = (const int*)d_in[8];
    const int* dst = (const int*)d_in[9];
    float* out = (float*)d_out;

    if (ws_size >= WS_NEED) {
        char* ws = (char*)d_ws;
        int* start = (int*)(ws + START_OFF);
        int* fill  = (int*)(ws + FILL_OFF);
        int* pos   = (int*)(ws + POS_OFF);
        int* bsum  = pos;   // scratch reuse: pos not yet written during scan
        unsigned short* msg = (unsigned short*)(ws + MSG_OFF);

        const int n_scan = N_NODES + 1;
        const int nb = (n_scan + 255) / 256;   // 196

        kz<<<(n_scan + 255) / 256, 256, 0, stream>>>(start, n_scan);
        kh<<<(N_EDGES + 255) / 256, 256, 0, stream>>>(dst, start);
        ks1<<<nb, 256, 0, stream>>>(start, bsum, n_scan);
        ks2<<<1, 256, 0, stream>>>(bsum, nb);
        ks3<<<nb, 256, 0, stream>>>(bsum, start, fill, n_scan);
        kpos<<<(N_EDGES + 255) / 256, 256, 0, stream>>>(dst, fill, pos);

        // phase 1: messages -> msgbuf (bf16, CSR order), no atomics
        k_edge_msg<<<N_EDGES / (16 * 8 * 2), 512, 0, stream>>>(
            ef, nf, W0, b0, W1, b1, src, pos, msg);
        // phase 2: rst = nf + segment-sum(msg) -> d_out
        k_reduce<<<(N_NODES + 3) / 4, 256, 0, stream>>>(nf, msg, start, out);
    } else {
        // fallback: atomic scatter path
        k_copy<<<2048, 256, 0, stream>>>((const f32x4*)nf, (f32x4*)out, N_NODES * D_NODE / 4);
        k_edge<<<N_EDGES / (16 * 4 * 4), 256, 0, stream>>>(ef, nf, W0, b0, W1, b1, src, dst, out);
    }

    // out = rst @ Wa + ba (in place)
    k_out<<<(N_NODES / 16 + 3) / 4, 256, 0, stream>>>(Wa, ba, out);
}

// Round 6
// 302.985 us; speedup vs baseline: 1.5453x; 1.1288x over previous
//
#include <hip/hip_runtime.h>

typedef short bf16x8 __attribute__((ext_vector_type(8)));
typedef float f32x4 __attribute__((ext_vector_type(4)));
typedef unsigned short u16x4 __attribute__((ext_vector_type(4)));
typedef unsigned short u16x8 __attribute__((ext_vector_type(8)));

static constexpr int N_NODES = 50000;
static constexpr int N_EDGES = 800000;
static constexpr int D_NODE = 128;
static constexpr int D_EDGE = 64;

// workspace layout (bytes)
static constexpr size_t START_OFF = 0;                       // (N_NODES+1) ints
static constexpr size_t FILL_OFF  = 262144;                  // N_NODES ints
static constexpr size_t POS_OFF   = 524288;                  // N_EDGES ints (also bsum scratch)
static constexpr size_t MSG_OFF   = POS_OFF + (size_t)N_EDGES * 4;
static constexpr size_t WS_NEED   = MSG_OFF + (size_t)N_EDGES * D_NODE * 2;

__device__ __forceinline__ unsigned short f2bf(float f) {
    union { float f; unsigned u; } v; v.f = f;
    return (unsigned short)((v.u + 0x7fffu + ((v.u >> 16) & 1u)) >> 16);
}
__device__ __forceinline__ float bf2f(unsigned short h) {
    union { unsigned u; float f; } v; v.u = ((unsigned)h) << 16;
    return v.f;
}

// =============== preprocessing: CSR of edges by dst ==========================
__global__ void kz(int* __restrict__ a, int n) {
    int i = blockIdx.x * blockDim.x + threadIdx.x;
    if (i < n) a[i] = 0;
}

__global__ void kh(const int* __restrict__ dst, int* __restrict__ start) {
    int e = blockIdx.x * blockDim.x + threadIdx.x;
    if (e < N_EDGES) atomicAdd(&start[dst[e] + 1], 1);
}

// hierarchical scan over start[0..n-1], n = N_NODES+1, 256-elem blocks
__global__ __launch_bounds__(256) void ks1(const int* __restrict__ a, int* __restrict__ bsum, int n) {
    __shared__ int sd[256];
    const int t = threadIdx.x;
    int i = blockIdx.x * 256 + t;
    sd[t] = (i < n) ? a[i] : 0;
    __syncthreads();
    for (int off = 128; off > 0; off >>= 1) {
        if (t < off) sd[t] += sd[t + off];
        __syncthreads();
    }
    if (t == 0) bsum[blockIdx.x] = sd[0];
}

__global__ __launch_bounds__(256) void ks2(int* __restrict__ bsum, int nb) {
    __shared__ int sd[256];
    const int t = threadIdx.x;
    sd[t] = (t < nb) ? bsum[t] : 0;
    __syncthreads();
    for (int off = 1; off < 256; off <<= 1) {
        int v = (t >= off) ? sd[t - off] : 0;
        __syncthreads();
        sd[t] += v;
        __syncthreads();
    }
    if (t < nb) bsum[t] = sd[t];
}

__global__ __launch_bounds__(256) void ks3(const int* __restrict__ bsum,
                                           int* __restrict__ start, int* __restrict__ fill, int n) {
    __shared__ int sd[256];
    const int t = threadIdx.x;
    const int i = blockIdx.x * 256 + t;
    sd[t] = (i < n) ? start[i] : 0;
    __syncthreads();
    for (int off = 1; off < 256; off <<= 1) {
        int v = (t >= off) ? sd[t - off] : 0;
        __syncthreads();
        sd[t] += v;
        __syncthreads();
    }
    const int off0 = (blockIdx.x > 0) ? bsum[blockIdx.x - 1] : 0;
    const int val = sd[t] + off0;
    if (i < n) start[i] = val;
    if (i < N_NODES) fill[i] = val;
}

__global__ void kpos(const int* __restrict__ dst, int* __restrict__ fill, int* __restrict__ pos) {
    int e = blockIdx.x * blockDim.x + threadIdx.x;
    if (e < N_EDGES) pos[e] = atomicAdd(&fill[dst[e]], 1);
}

// =============== phase 1: edge MLP -> bf16 message rows at CSR position ======
// 256 threads, 4 waves, 4 tiles of 16 edges per wave.
// Gather loads are ISSUED BEFORE the MFMA block (after ef loads) so their
// latency hides under the MLP compute (vmcnt completes in issue order).
__global__ __launch_bounds__(256) void k_edge_msg(
    const float* __restrict__ ef, const float* __restrict__ nf,
    const float* __restrict__ W0, const float* __restrict__ b0,
    const float* __restrict__ W1, const float* __restrict__ b1,
    const int* __restrict__ src, const int* __restrict__ posp,
    unsigned short* __restrict__ msg)
{
    __shared__ unsigned short w0f[2 * 4 * 64 * 8];           // 8 KB
    __shared__ unsigned short w1f[2 * 8 * 64 * 8];           // 16 KB
    __shared__ __align__(16) unsigned short hT[4][16][72];   // layer-1 transpose
    __shared__ __align__(16) unsigned short mT[4][16][136];  // message tile

    const int tid = threadIdx.x;
    for (int f = tid; f < 4096; f += 256) {
        int j = f & 7, lane = (f >> 3) & 63, nt = (f >> 9) & 3, ks = (f >> 11) & 1;
        int k = ks * 32 + ((lane >> 4) << 2) + (j & 3) + ((j & 4) << 2);
        int n = nt * 16 + (lane & 15);
        w0f[f] = f2bf(W0[k * 64 + n]);
    }
    for (int f = tid; f < 8192; f += 256) {
        int j = f & 7, lane = (f >> 3) & 63, nt = (f >> 9) & 7, ks = (f >> 12) & 1;
        int k = ks * 32 + ((lane >> 4) << 2) + (j & 3) + ((j & 4) << 2);
        int n = nt * 16 + (lane & 15);
        w1f[f] = f2bf(W1[k * 128 + n]);
    }
    __syncthreads();

    const int wv = tid >> 6;
    const int lane = tid & 63;
    const int lm = lane & 15;
    const int lq = lane >> 4;

    float b0r[4], b1r[8];
#pragma unroll
    for (int nt = 0; nt < 4; ++nt) b0r[nt] = b0[nt * 16 + lm];
#pragma unroll
    for (int nt = 0; nt < 8; ++nt) b1r[nt] = b1[nt * 16 + lm];

    const bf16x8* w0v = (const bf16x8*)w0f;
    const bf16x8* w1v = (const bf16x8*)w1f;

    const int wtile0 = (blockIdx.x * 4 + wv) * 4;

    // upfront index loads for all 4 tiles:
    //  sidx[t][r]: src row for combine rows lq*4+r (uniform across lm -> broadcast)
    //  pidx[t][p]: CSR position for store rows p*4+lq
    int sidx[4][4], pidx[4][4];
#pragma unroll
    for (int t = 0; t < 4; ++t) {
        const int ebase = (wtile0 + t) * 16;
#pragma unroll
        for (int r = 0; r < 4; ++r) sidx[t][r] = src[ebase + lq * 4 + r];
#pragma unroll
        for (int p = 0; p < 4; ++p) pidx[t][p] = posp[ebase + p * 4 + lq];
    }

    for (int t = 0; t < 4; ++t) {
        const int ebase = (wtile0 + t) * 16;

        // ---- ef loads FIRST (consumed first; vmcnt is in-order) ----
        const f32x4* er = (const f32x4*)(ef + (size_t)(ebase + lm) * D_EDGE);
        f32x4 a0 = er[lq];
        f32x4 a1 = er[4 + lq];
        f32x4 a2 = er[8 + lq];
        f32x4 a3 = er[12 + lq];

        // ---- issue gather loads NOW; consumed only after the MLP ----
        float ng[4][8];
#pragma unroll
        for (int r = 0; r < 4; ++r) {
            const float* nrow = nf + (size_t)sidx[t][r] * D_NODE;
#pragma unroll
            for (int nt = 0; nt < 8; ++nt) ng[r][nt] = nrow[nt * 16 + lm];
        }

        bf16x8 af0, af1;
#pragma unroll
        for (int j = 0; j < 4; ++j) {
            af0[j] = (short)f2bf(a0[j]); af0[j + 4] = (short)f2bf(a1[j]);
            af1[j] = (short)f2bf(a2[j]); af1[j + 4] = (short)f2bf(a3[j]);
        }

        // ---- layer 1 ----
        f32x4 h[4];
#pragma unroll
        for (int nt = 0; nt < 4; ++nt) h[nt] = f32x4{0.f, 0.f, 0.f, 0.f};
#pragma unroll
        for (int nt = 0; nt < 4; ++nt) {
            h[nt] = __builtin_amdgcn_mfma_f32_16x16x32_bf16(af0, w0v[(0 * 4 + nt) * 64 + lane], h[nt], 0, 0, 0);
            h[nt] = __builtin_amdgcn_mfma_f32_16x16x32_bf16(af1, w0v[(1 * 4 + nt) * 64 + lane], h[nt], 0, 0, 0);
        }
#pragma unroll
        for (int nt = 0; nt < 4; ++nt)
#pragma unroll
            for (int r = 0; r < 4; ++r) {
                float x = h[nt][r] + b0r[nt];
                hT[wv][lq * 4 + r][nt * 16 + lm] = f2bf(fmaxf(x, 0.f));
            }

        const unsigned short* hrow = &hT[wv][lm][0];
        u16x4 p0 = *(const u16x4*)(hrow + lq * 4);
        u16x4 p1 = *(const u16x4*)(hrow + 16 + lq * 4);
        u16x4 p2 = *(const u16x4*)(hrow + 32 + lq * 4);
        u16x4 p3 = *(const u16x4*)(hrow + 48 + lq * 4);
        bf16x8 g0, g1;
#pragma unroll
        for (int j = 0; j < 4; ++j) {
            g0[j] = (short)p0[j]; g0[j + 4] = (short)p1[j];
            g1[j] = (short)p2[j]; g1[j + 4] = (short)p3[j];
        }

        // ---- layer 2 ----
        f32x4 o[8];
#pragma unroll
        for (int nt = 0; nt < 8; ++nt) o[nt] = f32x4{0.f, 0.f, 0.f, 0.f};
#pragma unroll
        for (int nt = 0; nt < 8; ++nt) {
            o[nt] = __builtin_amdgcn_mfma_f32_16x16x32_bf16(g0, w1v[(0 * 8 + nt) * 64 + lane], o[nt], 0, 0, 0);
            o[nt] = __builtin_amdgcn_mfma_f32_16x16x32_bf16(g1, w1v[(1 * 8 + nt) * 64 + lane], o[nt], 0, 0, 0);
        }

        // ---- combine: e = relu(o+b1); m = relu(ng + e) -> mT (gathers done) ----
#pragma unroll
        for (int r = 0; r < 4; ++r)
#pragma unroll
            for (int nt = 0; nt < 8; ++nt) {
                float e2 = fmaxf(o[nt][r] + b1r[nt], 0.f);
                float x = e2 + ng[r][nt];
                mT[wv][lq * 4 + r][nt * 16 + lm] = f2bf(fmaxf(x, 0.f));
            }

        // ---- coalesced row stores: quarter lq writes rows p*4+lq ----
#pragma unroll
        for (int p = 0; p < 4; ++p) {
            const int row = p * 4 + lq;
            u16x8 v = *(const u16x8*)&mT[wv][row][lm * 8];
            *(u16x8*)(msg + (size_t)pidx[t][p] * D_NODE + lm * 8) = v;
        }
    }
}

// =============== phase 2: rst[v] = nf[v] + sum(msg rows of v) ================
// one full wave per node: quarter lq streams rows s+lq, s+lq+4, ...
__global__ __launch_bounds__(256) void k_reduce(
    const float* __restrict__ nf, const unsigned short* __restrict__ msg,
    const int* __restrict__ start, float* __restrict__ out)
{
    const int tid = threadIdx.x;
    const int wv = tid >> 6;
    const int lane = tid & 63;
    const int lq = lane >> 4;
    const int li = lane & 15;
    const int v = blockIdx.x * 4 + wv;
    if (v >= N_NODES) return;

    const int s = start[v];
    const int e = start[v + 1];

    f32x4 acc0 = f32x4{0.f, 0.f, 0.f, 0.f};
    f32x4 acc1 = f32x4{0.f, 0.f, 0.f, 0.f};

    for (int i = s + lq; i < e; i += 4) {
        u16x8 m = *(const u16x8*)(msg + (size_t)i * D_NODE + li * 8);
#pragma unroll
        for (int j = 0; j < 4; ++j) acc0[j] += bf2f(m[j]);
#pragma unroll
        for (int j = 0; j < 4; ++j) acc1[j] += bf2f(m[4 + j]);
    }

    // cross-quarter reduce (lanes lq*16+li, same li share columns)
#pragma unroll
    for (int j = 0; j < 4; ++j) {
        acc0[j] += __shfl_xor(acc0[j], 16);
        acc0[j] += __shfl_xor(acc0[j], 32);
        acc1[j] += __shfl_xor(acc1[j], 16);
        acc1[j] += __shfl_xor(acc1[j], 32);
    }

    if (lq == 0) {
        const f32x4* nrow = (const f32x4*)(nf + (size_t)v * D_NODE);
        f32x4* orow = (f32x4*)(out + (size_t)v * D_NODE);
        orow[li * 2] = nrow[li * 2] + acc0;
        orow[li * 2 + 1] = nrow[li * 2 + 1] + acc1;
    }
}

// =============== fallback path (atomic scatter), known-good ==================
__global__ void k_copy(const f32x4* __restrict__ s, f32x4* __restrict__ d, int n4) {
    int stride = gridDim.x * blockDim.x;
    for (int i = blockIdx.x * blockDim.x + threadIdx.x; i < n4; i += stride)
        d[i] = s[i];
}

__global__ __launch_bounds__(256) void k_edge(
    const float* __restrict__ ef, const float* __restrict__ nf,
    const float* __restrict__ W0, const float* __restrict__ b0,
    const float* __restrict__ W1, const float* __restrict__ b1,
    const int* __restrict__ src, const int* __restrict__ dst,
    float* __restrict__ acc)
{
    __shared__ unsigned short w0f[2 * 4 * 64 * 8];
    __shared__ unsigned short w1f[2 * 8 * 64 * 8];
    __shared__ unsigned short hT[4][16][72];

    const int tid = threadIdx.x;
    for (int f = tid; f < 4096; f += 256) {
        int j = f & 7, lane = (f >> 3) & 63, nt = (f >> 9) & 3, ks = (f >> 11) & 1;
        int k = ks * 32 + ((lane >> 4) << 2) + (j & 3) + ((j & 4) << 2);
        int n = nt * 16 + (lane & 15);
        w0f[f] = f2bf(W0[k * 64 + n]);
    }
    for (int f = tid; f < 8192; f += 256) {
        int j = f & 7, lane = (f >> 3) & 63, nt = (f >> 9) & 7, ks = (f >> 12) & 1;
        int k = ks * 32 + ((lane >> 4) << 2) + (j & 3) + ((j & 4) << 2);
        int n = nt * 16 + (lane & 15);
        w1f[f] = f2bf(W1[k * 128 + n]);
    }
    __syncthreads();

    const int wv = tid >> 6;
    const int lane = tid & 63;
    const int lm = lane & 15;
    const int lq = lane >> 4;

    float b0r[4], b1r[8];
#pragma unroll
    for (int nt = 0; nt < 4; ++nt) b0r[nt] = b0[nt * 16 + lm];
#pragma unroll
    for (int nt = 0; nt < 8; ++nt) b1r[nt] = b1[nt * 16 + lm];

    const bf16x8* w0v = (const bf16x8*)w0f;
    const bf16x8* w1v = (const bf16x8*)w1f;

    for (int t = 0; t < 4; ++t) {
        const int tile = (blockIdx.x * 4 + wv) * 4 + t;
        const int ebase = tile * 16;

        const f32x4* er = (const f32x4*)(ef + (size_t)(ebase + lm) * D_EDGE);
        f32x4 a0 = er[lq];
        f32x4 a1 = er[4 + lq];
        f32x4 a2 = er[8 + lq];
        f32x4 a3 = er[12 + lq];
        bf16x8 af0, af1;
#pragma unroll
        for (int j = 0; j < 4; ++j) {
            af0[j] = (short)f2bf(a0[j]); af0[j + 4] = (short)f2bf(a1[j]);
            af1[j] = (short)f2bf(a2[j]); af1[j + 4] = (short)f2bf(a3[j]);
        }

        f32x4 h[4];
#pragma unroll
        for (int nt = 0; nt < 4; ++nt) h[nt] = f32x4{0.f, 0.f, 0.f, 0.f};
#pragma unroll
        for (int nt = 0; nt < 4; ++nt) {
            h[nt] = __builtin_amdgcn_mfma_f32_16x16x32_bf16(af0, w0v[(0 * 4 + nt) * 64 + lane], h[nt], 0, 0, 0);
            h[nt] = __builtin_amdgcn_mfma_f32_16x16x32_bf16(af1, w0v[(1 * 4 + nt) * 64 + lane], h[nt], 0, 0, 0);
        }
#pragma unroll
        for (int nt = 0; nt < 4; ++nt)
#pragma unroll
            for (int r = 0; r < 4; ++r) {
                float x = h[nt][r] + b0r[nt];
                hT[wv][lq * 4 + r][nt * 16 + lm] = f2bf(fmaxf(x, 0.f));
            }

        const unsigned short* hrow = &hT[wv][lm][0];
        u16x4 p0 = *(const u16x4*)(hrow + lq * 4);
        u16x4 p1 = *(const u16x4*)(hrow + 16 + lq * 4);
        u16x4 p2 = *(const u16x4*)(hrow + 32 + lq * 4);
        u16x4 p3 = *(const u16x4*)(hrow + 48 + lq * 4);
        bf16x8 g0, g1;
#pragma unroll
        for (int j = 0; j < 4; ++j) {
            g0[j] = (short)p0[j]; g0[j + 4] = (short)p1[j];
            g1[j] = (short)p2[j]; g1[j + 4] = (short)p3[j];
        }

        f32x4 o[8];
#pragma unroll
        for (int nt = 0; nt < 8; ++nt) o[nt] = f32x4{0.f, 0.f, 0.f, 0.f};
#pragma unroll
        for (int nt = 0; nt < 8; ++nt) {
            o[nt] = __builtin_amdgcn_mfma_f32_16x16x32_bf16(g0, w1v[(0 * 8 + nt) * 64 + lane], o[nt], 0, 0, 0);
            o[nt] = __builtin_amdgcn_mfma_f32_16x16x32_bf16(g1, w1v[(1 * 8 + nt) * 64 + lane], o[nt], 0, 0, 0);
        }

        const int e0 = ebase + lq * 4;
        int s_[4], d_[4];
#pragma unroll
        for (int r = 0; r < 4; ++r) { s_[r] = src[e0 + r]; d_[r] = dst[e0 + r]; }
#pragma unroll
        for (int r = 0; r < 4; ++r) {
            const float* nrow = nf + (size_t)s_[r] * D_NODE;
            float* arow = acc + (size_t)d_[r] * D_NODE;
#pragma unroll
            for (int nt = 0; nt < 8; ++nt) {
                float e2 = fmaxf(o[nt][r] + b1r[nt], 0.f);
                float x = e2 + nrow[nt * 16 + lm];
                unsafeAtomicAdd(&arow[nt * 16 + lm], fmaxf(x, 0.f));
            }
        }
    }
}

// =============== kernel: out = acc @ Wa + ba, in place =======================
__global__ __launch_bounds__(256) void k_out(
    const float* __restrict__ Wa, const float* __restrict__ ba,
    float* __restrict__ out)
{
    __shared__ unsigned short waf[4 * 8 * 64 * 8];   // 32 KB

    const int tid = threadIdx.x;
    for (int f = tid; f < 16384; f += 256) {
        int j = f & 7, lane = (f >> 3) & 63, nt = (f >> 9) & 7, ks = (f >> 12) & 3;
        int k = ks * 32 + ((lane >> 4) << 2) + (j & 3) + ((j & 4) << 2);
        int n = nt * 16 + (lane & 15);
        waf[f] = f2bf(Wa[k * 128 + n]);
    }
    __syncthreads();

    const int wv = tid >> 6;
    const int lane = tid & 63;
    const int lm = lane & 15;
    const int lq = lane >> 4;

    const int tile = blockIdx.x * 4 + wv;
    if (tile >= N_NODES / 16) return;
    const int rbase = tile * 16;

    const f32x4* arow = (const f32x4*)(out + (size_t)(rbase + lm) * D_NODE);
    const bf16x8* wav = (const bf16x8*)waf;

    bf16x8 afr[4];
#pragma unroll
    for (int ks = 0; ks < 4; ++ks) {
        f32x4 y0 = arow[ks * 8 + lq];
        f32x4 y1 = arow[ks * 8 + 4 + lq];
#pragma unroll
        for (int j = 0; j < 4; ++j) {
            afr[ks][j] = (short)f2bf(y0[j]);
            afr[ks][j + 4] = (short)f2bf(y1[j]);
        }
    }

    float bar[8];
#pragma unroll
    for (int nt = 0; nt < 8; ++nt) bar[nt] = ba[nt * 16 + lm];

    f32x4 o[8];
#pragma unroll
    for (int nt = 0; nt < 8; ++nt) o[nt] = f32x4{0.f, 0.f, 0.f, 0.f};
#pragma unroll
    for (int ks = 0; ks < 4; ++ks)
#pragma unroll
        for (int nt = 0; nt < 8; ++nt)
            o[nt] = __builtin_amdgcn_mfma_f32_16x16x32_bf16(afr[ks], wav[(ks * 8 + nt) * 64 + lane], o[nt], 0, 0, 0);

#pragma unroll
    for (int nt = 0; nt < 8; ++nt)
#pragma unroll
        for (int r = 0; r < 4; ++r)
            out[(size_t)(rbase + lq * 4 + r) * D_NODE + nt * 16 + lm] = o[nt][r] + bar[nt];
}

extern "C" void kernel_launch(void* const* d_in, const int* in_sizes, int n_in,
                              void* d_out, int out_size, void* d_ws, size_t ws_size,
                              hipStream_t stream) {
    const float* nf = (const float*)d_in[0];
    const float* ef = (const float*)d_in[1];
    const float* W0 = (const float*)d_in[2];
    const float* b0 = (const float*)d_in[3];
    const float* W1 = (const float*)d_in[4];
    const float* b1 = (const float*)d_in[5];
    const float* Wa = (const float*)d_in[6];
    const float* ba = (const float*)d_in[7];
    const int* src = (const int*)d_in[8];
    const int* dst = (const int*)d_in[9];
    float* out = (float*)d_out;

    if (ws_size >= WS_NEED) {
        char* ws = (char*)d_ws;
        int* start = (int*)(ws + START_OFF);
        int* fill  = (int*)(ws + FILL_OFF);
        int* pos   = (int*)(ws + POS_OFF);
        int* bsum  = pos;   // scratch reuse: pos not yet written during scan
        unsigned short* msg = (unsigned short*)(ws + MSG_OFF);

        const int n_scan = N_NODES + 1;
        const int nb = (n_scan + 255) / 256;   // 196

        kz<<<(n_scan + 255) / 256, 256, 0, stream>>>(start, n_scan);
        kh<<<(N_EDGES + 255) / 256, 256, 0, stream>>>(dst, start);
        ks1<<<nb, 256, 0, stream>>>(start, bsum, n_scan);
        ks2<<<1, 256, 0, stream>>>(bsum, nb);
        ks3<<<nb, 256, 0, stream>>>(bsum, start, fill, n_scan);
        kpos<<<(N_EDGES + 255) / 256, 256, 0, stream>>>(dst, fill, pos);

        // phase 1: messages -> msgbuf (bf16, CSR order), no atomics
        k_edge_msg<<<N_EDGES / (16 * 4 * 4), 256, 0, stream>>>(
            ef, nf, W0, b0, W1, b1, src, pos, msg);
        // phase 2: rst = nf + segment-sum(msg) -> d_out
        k_reduce<<<(N_NODES + 3) / 4, 256, 0, stream>>>(nf, msg, start, out);
    } else {
        // fallback: atomic scatter path
        k_copy<<<2048, 256, 0, stream>>>((const f32x4*)nf, (f32x4*)out, N_NODES * D_NODE / 4);
        k_edge<<<N_EDGES / (16 * 4 * 4), 256, 0, stream>>>(ef, nf, W0, b0, W1, b1, src, dst, out);
    }

    // out = rst @ Wa + ba (in place)
    k_out<<<(N_NODES / 16 + 3) / 4, 256, 0, stream>>>(Wa, ba, out);
}

// Round 8
// 290.139 us; speedup vs baseline: 1.6137x; 1.0443x over previous
//
#include <hip/hip_runtime.h>

typedef short bf16x8 __attribute__((ext_vector_type(8)));
typedef float f32x4 __attribute__((ext_vector_type(4)));
typedef unsigned short u16x2 __attribute__((ext_vector_type(2)));
typedef unsigned short u16x4 __attribute__((ext_vector_type(4)));
typedef unsigned short u16x8 __attribute__((ext_vector_type(8)));

static constexpr int N_NODES = 50000;
static constexpr int N_EDGES = 800000;
static constexpr int D_NODE = 128;
static constexpr int D_EDGE = 64;

// workspace layout (bytes)
static constexpr size_t START_OFF = 0;                      // (N_NODES+1) ints
static constexpr size_t FILL_OFF  = 262144;                 // N_NODES ints
static constexpr size_t PERM_OFF  = 524288;                 // N_EDGES ints (also bsum scratch)
static constexpr size_t SRCP_OFF  = PERM_OFF + (size_t)N_EDGES * 4;
static constexpr size_t DSTP_OFF  = SRCP_OFF + (size_t)N_EDGES * 4;
static constexpr size_t WS_NEED   = DSTP_OFF + (size_t)N_EDGES * 4;

__device__ __forceinline__ unsigned short f2bf(float f) {
    union { float f; unsigned u; } v; v.f = f;
    return (unsigned short)((v.u + 0x7fffu + ((v.u >> 16) & 1u)) >> 16);
}
__device__ __forceinline__ float bf2f(unsigned short h) {
    union { unsigned u; float f; } v; v.u = ((unsigned)h) << 16;
    return v.f;
}

// =============== preprocessing: CSR permutation of edges by dst ==============
__global__ void kz(int* __restrict__ a, int n) {
    int i = blockIdx.x * blockDim.x + threadIdx.x;
    if (i < n) a[i] = 0;
}

__global__ void kh(const int* __restrict__ dst, int* __restrict__ start) {
    int e = blockIdx.x * blockDim.x + threadIdx.x;
    if (e < N_EDGES) atomicAdd(&start[dst[e] + 1], 1);
}

// hierarchical scan over start[0..n-1], n = N_NODES+1, 256-elem blocks
__global__ __launch_bounds__(256) void ks1(const int* __restrict__ a, int* __restrict__ bsum, int n) {
    __shared__ int sd[256];
    const int t = threadIdx.x;
    int i = blockIdx.x * 256 + t;
    sd[t] = (i < n) ? a[i] : 0;
    __syncthreads();
    for (int off = 128; off > 0; off >>= 1) {
        if (t < off) sd[t] += sd[t + off];
        __syncthreads();
    }
    if (t == 0) bsum[blockIdx.x] = sd[0];
}

__global__ __launch_bounds__(256) void ks2(int* __restrict__ bsum, int nb) {
    __shared__ int sd[256];
    const int t = threadIdx.x;
    sd[t] = (t < nb) ? bsum[t] : 0;
    __syncthreads();
    for (int off = 1; off < 256; off <<= 1) {
        int v = (t >= off) ? sd[t - off] : 0;
        __syncthreads();
        sd[t] += v;
        __syncthreads();
    }
    if (t < nb) bsum[t] = sd[t];
}

__global__ __launch_bounds__(256) void ks3(const int* __restrict__ bsum,
                                           int* __restrict__ start, int* __restrict__ fill, int n) {
    __shared__ int sd[256];
    const int t = threadIdx.x;
    const int i = blockIdx.x * 256 + t;
    sd[t] = (i < n) ? start[i] : 0;
    __syncthreads();
    for (int off = 1; off < 256; off <<= 1) {
        int v = (t >= off) ? sd[t - off] : 0;
        __syncthreads();
        sd[t] += v;
        __syncthreads();
    }
    const int off0 = (blockIdx.x > 0) ? bsum[blockIdx.x - 1] : 0;
    const int val = sd[t] + off0;
    if (i < n) start[i] = val;
    if (i < N_NODES) fill[i] = val;
}

// build CSR order: perm[p] = edge id; pre-gather src/dst into CSR order
__global__ void kpos(const int* __restrict__ dst, const int* __restrict__ src,
                     int* __restrict__ fill, int* __restrict__ perm,
                     int* __restrict__ srcp, int* __restrict__ dstp) {
    int e = blockIdx.x * blockDim.x + threadIdx.x;
    if (e < N_EDGES) {
        int d = dst[e];
        int p = atomicAdd(&fill[d], 1);
        perm[p] = e;
        srcp[p] = src[e];
        dstp[p] = d;
    }
}

// =============== fused: edge MLP (CSR order) + inline segment reduce =========
// 256 threads, 4 waves, 4 tiles of 16 CSR-ordered edges per wave.
// Messages never touch HBM: tile in LDS -> per-column serial segment sum ->
// one fp32 atomicAdd per (node,tile) boundary (~2-3 per tile).
__global__ __launch_bounds__(256) void k_edge_fused(
    const float* __restrict__ ef, const float* __restrict__ nf,
    const float* __restrict__ W0, const float* __restrict__ b0,
    const float* __restrict__ W1, const float* __restrict__ b1,
    const int* __restrict__ perm, const int* __restrict__ srcp,
    const int* __restrict__ dstp, float* __restrict__ out)
{
    __shared__ unsigned short w0f[2 * 4 * 64 * 8];           // 8 KB
    __shared__ unsigned short w1f[2 * 8 * 64 * 8];           // 16 KB
    __shared__ __align__(16) unsigned short hT[4][16][72];   // layer-1 transpose
    __shared__ __align__(16) unsigned short mT[4][16][136];  // message tile

    const int tid = threadIdx.x;
    for (int f = tid; f < 4096; f += 256) {
        int j = f & 7, lane = (f >> 3) & 63, nt = (f >> 9) & 3, ks = (f >> 11) & 1;
        int k = ks * 32 + ((lane >> 4) << 2) + (j & 3) + ((j & 4) << 2);
        int n = nt * 16 + (lane & 15);
        w0f[f] = f2bf(W0[k * 64 + n]);
    }
    for (int f = tid; f < 8192; f += 256) {
        int j = f & 7, lane = (f >> 3) & 63, nt = (f >> 9) & 7, ks = (f >> 12) & 1;
        int k = ks * 32 + ((lane >> 4) << 2) + (j & 3) + ((j & 4) << 2);
        int n = nt * 16 + (lane & 15);
        w1f[f] = f2bf(W1[k * 128 + n]);
    }
    __syncthreads();

    const int wv = tid >> 6;
    const int lane = tid & 63;
    const int lm = lane & 15;
    const int lq = lane >> 4;

    float b0r[4], b1r[8];
#pragma unroll
    for (int nt = 0; nt < 4; ++nt) b0r[nt] = b0[nt * 16 + lm];
#pragma unroll
    for (int nt = 0; nt < 8; ++nt) b1r[nt] = b1[nt * 16 + lm];

    const bf16x8* w0v = (const bf16x8*)w0f;
    const bf16x8* w1v = (const bf16x8*)w1f;

    const int wtile0 = (blockIdx.x * 4 + wv) * 4;

    for (int t = 0; t < 4; ++t) {
        const int ebase = (wtile0 + t) * 16;

        // ---- per-row meta (coalesced; lane holds row lm's values) ----
        const int e_m = perm[ebase + lm];
        const int s_m = srcp[ebase + lm];
        const int d_m = dstp[ebase + lm];

        // ---- ef row lm (random 256-B row, fully consumed) ----
        const f32x4* er = (const f32x4*)(ef + (size_t)e_m * D_EDGE);
        f32x4 a0 = er[lq];
        f32x4 a1 = er[4 + lq];
        f32x4 a2 = er[8 + lq];
        f32x4 a3 = er[12 + lq];

        // ---- issue node-feature gathers early (hidden under MLP) ----
        float ng[4][8];
#pragma unroll
        for (int r = 0; r < 4; ++r) {
            const int s_row = __shfl(s_m, lq * 4 + r);
            const float* nrow = nf + (size_t)s_row * D_NODE;
#pragma unroll
            for (int nt = 0; nt < 8; ++nt) ng[r][nt] = nrow[nt * 16 + lm];
        }

        bf16x8 af0, af1;
#pragma unroll
        for (int j = 0; j < 4; ++j) {
            af0[j] = (short)f2bf(a0[j]); af0[j + 4] = (short)f2bf(a1[j]);
            af1[j] = (short)f2bf(a2[j]); af1[j + 4] = (short)f2bf(a3[j]);
        }

        // ---- layer 1 ----
        f32x4 h[4];
#pragma unroll
        for (int nt = 0; nt < 4; ++nt) h[nt] = f32x4{0.f, 0.f, 0.f, 0.f};
#pragma unroll
        for (int nt = 0; nt < 4; ++nt) {
            h[nt] = __builtin_amdgcn_mfma_f32_16x16x32_bf16(af0, w0v[(0 * 4 + nt) * 64 + lane], h[nt], 0, 0, 0);
            h[nt] = __builtin_amdgcn_mfma_f32_16x16x32_bf16(af1, w0v[(1 * 4 + nt) * 64 + lane], h[nt], 0, 0, 0);
        }
#pragma unroll
        for (int nt = 0; nt < 4; ++nt)
#pragma unroll
            for (int r = 0; r < 4; ++r) {
                float x = h[nt][r] + b0r[nt];
                hT[wv][lq * 4 + r][nt * 16 + lm] = f2bf(fmaxf(x, 0.f));
            }

        const unsigned short* hrow = &hT[wv][lm][0];
        u16x4 p0 = *(const u16x4*)(hrow + lq * 4);
        u16x4 p1 = *(const u16x4*)(hrow + 16 + lq * 4);
        u16x4 p2 = *(const u16x4*)(hrow + 32 + lq * 4);
        u16x4 p3 = *(const u16x4*)(hrow + 48 + lq * 4);
        bf16x8 g0, g1;
#pragma unroll
        for (int j = 0; j < 4; ++j) {
            g0[j] = (short)p0[j]; g0[j + 4] = (short)p1[j];
            g1[j] = (short)p2[j]; g1[j + 4] = (short)p3[j];
        }

        // ---- layer 2 ----
        f32x4 o[8];
#pragma unroll
        for (int nt = 0; nt < 8; ++nt) o[nt] = f32x4{0.f, 0.f, 0.f, 0.f};
#pragma unroll
        for (int nt = 0; nt < 8; ++nt) {
            o[nt] = __builtin_amdgcn_mfma_f32_16x16x32_bf16(g0, w1v[(0 * 8 + nt) * 64 + lane], o[nt], 0, 0, 0);
            o[nt] = __builtin_amdgcn_mfma_f32_16x16x32_bf16(g1, w1v[(1 * 8 + nt) * 64 + lane], o[nt], 0, 0, 0);
        }

        // ---- combine: e = relu(o+b1); m = relu(ng + e) -> mT ----
#pragma unroll
        for (int r = 0; r < 4; ++r)
#pragma unroll
            for (int nt = 0; nt < 8; ++nt) {
                float e2 = fmaxf(o[nt][r] + b1r[nt], 0.f);
                float x = e2 + ng[r][nt];
                mT[wv][lq * 4 + r][nt * 16 + lm] = f2bf(fmaxf(x, 0.f));
            }

        // make mT writes visible/ordered before the cross-lane reads below
        asm volatile("" ::: "memory");
        __syncthreads();   // uniform across block (all waves run t=0..3)

        // ---- inline segment-sum: lane owns cols {lane*2, lane*2+1} ----
        // rows are dst-sorted; flush fp32 partials at boundaries via atomics
        float acc0 = 0.f, acc1 = 0.f;
        int dprev = __shfl(d_m, 0);
#pragma unroll
        for (int r = 0; r < 16; ++r) {
            const int dr = __shfl(d_m, r);
            if (dr != dprev) {                    // wave-uniform condition
                float* orow = out + (size_t)dprev * D_NODE + lane * 2;
                unsafeAtomicAdd(orow, acc0);
                unsafeAtomicAdd(orow + 1, acc1);
                acc0 = 0.f; acc1 = 0.f; dprev = dr;
            }
            const u16x2 v = *(const u16x2*)&mT[wv][r][lane * 2];   // typed load (no TBAA UB)
            acc0 += bf2f(v[0]);
            acc1 += bf2f(v[1]);
        }
        float* orow = out + (size_t)dprev * D_NODE + lane * 2;
        unsafeAtomicAdd(orow, acc0);
        unsafeAtomicAdd(orow + 1, acc1);

        asm volatile("" ::: "memory");   // keep next tile's writes below these reads
    }
}

// =============== kernel: acc init (out = nf) =================================
__global__ void k_copy(const f32x4* __restrict__ s, f32x4* __restrict__ d, int n4) {
    int stride = gridDim.x * blockDim.x;
    for (int i = blockIdx.x * blockDim.x + threadIdx.x; i < n4; i += stride)
        d[i] = s[i];
}

// =============== fallback path (atomic scatter), known-good ==================
__global__ __launch_bounds__(256) void k_edge(
    const float* __restrict__ ef, const float* __restrict__ nf,
    const float* __restrict__ W0, const float* __restrict__ b0,
    const float* __restrict__ W1, const float* __restrict__ b1,
    const int* __restrict__ src, const int* __restrict__ dst,
    float* __restrict__ acc)
{
    __shared__ unsigned short w0f[2 * 4 * 64 * 8];
    __shared__ unsigned short w1f[2 * 8 * 64 * 8];
    __shared__ unsigned short hT[4][16][72];

    const int tid = threadIdx.x;
    for (int f = tid; f < 4096; f += 256) {
        int j = f & 7, lane = (f >> 3) & 63, nt = (f >> 9) & 3, ks = (f >> 11) & 1;
        int k = ks * 32 + ((lane >> 4) << 2) + (j & 3) + ((j & 4) << 2);
        int n = nt * 16 + (lane & 15);
        w0f[f] = f2bf(W0[k * 64 + n]);
    }
    for (int f = tid; f < 8192; f += 256) {
        int j = f & 7, lane = (f >> 3) & 63, nt = (f >> 9) & 7, ks = (f >> 12) & 1;
        int k = ks * 32 + ((lane >> 4) << 2) + (j & 3) + ((j & 4) << 2);
        int n = nt * 16 + (lane & 15);
        w1f[f] = f2bf(W1[k * 128 + n]);
    }
    __syncthreads();

    const int wv = tid >> 6;
    const int lane = tid & 63;
    const int lm = lane & 15;
    const int lq = lane >> 4;

    float b0r[4], b1r[8];
#pragma unroll
    for (int nt = 0; nt < 4; ++nt) b0r[nt] = b0[nt * 16 + lm];
#pragma unroll
    for (int nt = 0; nt < 8; ++nt) b1r[nt] = b1[nt * 16 + lm];

    const bf16x8* w0v = (const bf16x8*)w0f;
    const bf16x8* w1v = (const bf16x8*)w1f;

    for (int t = 0; t < 4; ++t) {
        const int tile = (blockIdx.x * 4 + wv) * 4 + t;
        const int ebase = tile * 16;

        const f32x4* er = (const f32x4*)(ef + (size_t)(ebase + lm) * D_EDGE);
        f32x4 a0 = er[lq];
        f32x4 a1 = er[4 + lq];
        f32x4 a2 = er[8 + lq];
        f32x4 a3 = er[12 + lq];
        bf16x8 af0, af1;
#pragma unroll
        for (int j = 0; j < 4; ++j) {
            af0[j] = (short)f2bf(a0[j]); af0[j + 4] = (short)f2bf(a1[j]);
            af1[j] = (short)f2bf(a2[j]); af1[j + 4] = (short)f2bf(a3[j]);
        }

        f32x4 h[4];
#pragma unroll
        for (int nt = 0; nt < 4; ++nt) h[nt] = f32x4{0.f, 0.f, 0.f, 0.f};
#pragma unroll
        for (int nt = 0; nt < 4; ++nt) {
            h[nt] = __builtin_amdgcn_mfma_f32_16x16x32_bf16(af0, w0v[(0 * 4 + nt) * 64 + lane], h[nt], 0, 0, 0);
            h[nt] = __builtin_amdgcn_mfma_f32_16x16x32_bf16(af1, w0v[(1 * 4 + nt) * 64 + lane], h[nt], 0, 0, 0);
        }
#pragma unroll
        for (int nt = 0; nt < 4; ++nt)
#pragma unroll
            for (int r = 0; r < 4; ++r) {
                float x = h[nt][r] + b0r[nt];
                hT[wv][lq * 4 + r][nt * 16 + lm] = f2bf(fmaxf(x, 0.f));
            }

        const unsigned short* hrow = &hT[wv][lm][0];
        u16x4 p0 = *(const u16x4*)(hrow + lq * 4);
        u16x4 p1 = *(const u16x4*)(hrow + 16 + lq * 4);
        u16x4 p2 = *(const u16x4*)(hrow + 32 + lq * 4);
        u16x4 p3 = *(const u16x4*)(hrow + 48 + lq * 4);
        bf16x8 g0, g1;
#pragma unroll
        for (int j = 0; j < 4; ++j) {
            g0[j] = (short)p0[j]; g0[j + 4] = (short)p1[j];
            g1[j] = (short)p2[j]; g1[j + 4] = (short)p3[j];
        }

        f32x4 o[8];
#pragma unroll
        for (int nt = 0; nt < 8; ++nt) o[nt] = f32x4{0.f, 0.f, 0.f, 0.f};
#pragma unroll
        for (int nt = 0; nt < 8; ++nt) {
            o[nt] = __builtin_amdgcn_mfma_f32_16x16x32_bf16(g0, w1v[(0 * 8 + nt) * 64 + lane], o[nt], 0, 0, 0);
            o[nt] = __builtin_amdgcn_mfma_f32_16x16x32_bf16(g1, w1v[(1 * 8 + nt) * 64 + lane], o[nt], 0, 0, 0);
        }

        const int e0 = ebase + lq * 4;
        int s_[4], d_[4];
#pragma unroll
        for (int r = 0; r < 4; ++r) { s_[r] = src[e0 + r]; d_[r] = dst[e0 + r]; }
#pragma unroll
        for (int r = 0; r < 4; ++r) {
            const float* nrow = nf + (size_t)s_[r] * D_NODE;
            float* arow = acc + (size_t)d_[r] * D_NODE;
#pragma unroll
            for (int nt = 0; nt < 8; ++nt) {
                float e2 = fmaxf(o[nt][r] + b1r[nt], 0.f);
                float x = e2 + nrow[nt * 16 + lm];
                unsafeAtomicAdd(&arow[nt * 16 + lm], fmaxf(x, 0.f));
            }
        }
    }
}

// =============== kernel: out = acc @ Wa + ba, in place =======================
__global__ __launch_bounds__(256) void k_out(
    const float* __restrict__ Wa, const float* __restrict__ ba,
    float* __restrict__ out)
{
    __shared__ unsigned short waf[4 * 8 * 64 * 8];   // 32 KB

    const int tid = threadIdx.x;
    for (int f = tid; f < 16384; f += 256) {
        int j = f & 7, lane = (f >> 3) & 63, nt = (f >> 9) & 7, ks = (f >> 12) & 3;
        int k = ks * 32 + ((lane >> 4) << 2) + (j & 3) + ((j & 4) << 2);
        int n = nt * 16 + (lane & 15);
        waf[f] = f2bf(Wa[k * 128 + n]);
    }
    __syncthreads();

    const int wv = tid >> 6;
    const int lane = tid & 63;
    const int lm = lane & 15;
    const int lq = lane >> 4;

    const int tile = blockIdx.x * 4 + wv;
    if (tile >= N_NODES / 16) return;
    const int rbase = tile * 16;

    const f32x4* arow = (const f32x4*)(out + (size_t)(rbase + lm) * D_NODE);
    const bf16x8* wav = (const bf16x8*)waf;

    bf16x8 afr[4];
#pragma unroll
    for (int ks = 0; ks < 4; ++ks) {
        f32x4 y0 = arow[ks * 8 + lq];
        f32x4 y1 = arow[ks * 8 + 4 + lq];
#pragma unroll
        for (int j = 0; j < 4; ++j) {
            afr[ks][j] = (short)f2bf(y0[j]);
            afr[ks][j + 4] = (short)f2bf(y1[j]);
        }
    }

    float bar[8];
#pragma unroll
    for (int nt = 0; nt < 8; ++nt) bar[nt] = ba[nt * 16 + lm];

    f32x4 o[8];
#pragma unroll
    for (int nt = 0; nt < 8; ++nt) o[nt] = f32x4{0.f, 0.f, 0.f, 0.f};
#pragma unroll
    for (int ks = 0; ks < 4; ++ks)
#pragma unroll
        for (int nt = 0; nt < 8; ++nt)
            o[nt] = __builtin_amdgcn_mfma_f32_16x16x32_bf16(afr[ks], wav[(ks * 8 + nt) * 64 + lane], o[nt], 0, 0, 0);

#pragma unroll
    for (int nt = 0; nt < 8; ++nt)
#pragma unroll
        for (int r = 0; r < 4; ++r)
            out[(size_t)(rbase + lq * 4 + r) * D_NODE + nt * 16 + lm] = o[nt][r] + bar[nt];
}

extern "C" void kernel_launch(void* const* d_in, const int* in_sizes, int n_in,
                              void* d_out, int out_size, void* d_ws, size_t ws_size,
                              hipStream_t stream) {
    const float* nf = (const float*)d_in[0];
    const float* ef = (const float*)d_in[1];
    const float* W0 = (const float*)d_in[2];
    const float* b0 = (const float*)d_in[3];
    const float* W1 = (const float*)d_in[4];
    const float* b1 = (const float*)d_in[5];
    const float* Wa = (const float*)d_in[6];
    const float* ba = (const float*)d_in[7];
    const int* src = (const int*)d_in[8];
    const int* dst = (const int*)d_in[9];
    float* out = (float*)d_out;

    // out = node_feat ((1+eps)*x term, eps=0) — both paths accumulate into it
    k_copy<<<2048, 256, 0, stream>>>((const f32x4*)nf, (f32x4*)out, N_NODES * D_NODE / 4);

    if (ws_size >= WS_NEED) {
        char* ws = (char*)d_ws;
        int* start = (int*)(ws + START_OFF);
        int* fill  = (int*)(ws + FILL_OFF);
        int* perm  = (int*)(ws + PERM_OFF);
        int* srcp  = (int*)(ws + SRCP_OFF);
        int* dstp  = (int*)(ws + DSTP_OFF);
        int* bsum  = perm;   // scratch reuse: perm not yet written during scan

        const int n_scan = N_NODES + 1;
        const int nb = (n_scan + 255) / 256;   // 196

        kz<<<(n_scan + 255) / 256, 256, 0, stream>>>(start, n_scan);
        kh<<<(N_EDGES + 255) / 256, 256, 0, stream>>>(dst, start);
        ks1<<<nb, 256, 0, stream>>>(start, bsum, n_scan);
        ks2<<<1, 256, 0, stream>>>(bsum, nb);
        ks3<<<nb, 256, 0, stream>>>(bsum, start, fill, n_scan);
        kpos<<<(N_EDGES + 255) / 256, 256, 0, stream>>>(dst, src, fill, perm, srcp, dstp);

        // fused: edge MLP in CSR order + inline segment reduce -> atomic partials
        k_edge_fused<<<N_EDGES / (16 * 4 * 4), 256, 0, stream>>>(
            ef, nf, W0, b0, W1, b1, perm, srcp, dstp, out);
    } else {
        // fallback: atomic scatter path
        k_edge<<<N_EDGES / (16 * 4 * 4), 256, 0, stream>>>(ef, nf, W0, b0, W1, b1, src, dst, out);
    }

    // out = rst @ Wa + ba (in place)
    k_out<<<(N_NODES / 16 + 3) / 4, 256, 0, stream>>>(Wa, ba, out);
}

// Round 9
// 276.944 us; speedup vs baseline: 1.6906x; 1.0476x over previous
//
#include <hip/hip_runtime.h>

typedef short bf16x8 __attribute__((ext_vector_type(8)));
typedef float f32x4 __attribute__((ext_vector_type(4)));
typedef unsigned short u16x2 __attribute__((ext_vector_type(2)));
typedef unsigned short u16x4 __attribute__((ext_vector_type(4)));
typedef unsigned short u16x8 __attribute__((ext_vector_type(8)));

static constexpr int N_NODES = 50000;
static constexpr int N_EDGES = 800000;
static constexpr int D_NODE = 128;
static constexpr int D_EDGE = 64;

// workspace layout (bytes)
static constexpr size_t START_OFF = 0;                      // (N_NODES+1) ints
static constexpr size_t FILL_OFF  = 262144;                 // N_NODES ints
static constexpr size_t PERM_OFF  = 524288;                 // N_EDGES ints (also bsum scratch)
static constexpr size_t SRCP_OFF  = PERM_OFF + (size_t)N_EDGES * 4;
static constexpr size_t DSTP_OFF  = SRCP_OFF + (size_t)N_EDGES * 4;
static constexpr size_t NF16_OFF  = DSTP_OFF + (size_t)N_EDGES * 4;
static constexpr size_t WS_NEED   = NF16_OFF + (size_t)N_NODES * D_NODE * 2;

__device__ __forceinline__ unsigned short f2bf(float f) {
    union { float f; unsigned u; } v; v.f = f;
    return (unsigned short)((v.u + 0x7fffu + ((v.u >> 16) & 1u)) >> 16);
}
__device__ __forceinline__ float bf2f(unsigned short h) {
    union { unsigned u; float f; } v; v.u = ((unsigned)h) << 16;
    return v.f;
}

// =============== preprocessing: CSR permutation of edges by dst ==============
__global__ void kz(int* __restrict__ a, int n) {
    int i = blockIdx.x * blockDim.x + threadIdx.x;
    if (i < n) a[i] = 0;
}

__global__ void kh(const int* __restrict__ dst, int* __restrict__ start) {
    int e = blockIdx.x * blockDim.x + threadIdx.x;
    if (e < N_EDGES) atomicAdd(&start[dst[e] + 1], 1);
}

// hierarchical scan over start[0..n-1], n = N_NODES+1, 256-elem blocks
__global__ __launch_bounds__(256) void ks1(const int* __restrict__ a, int* __restrict__ bsum, int n) {
    __shared__ int sd[256];
    const int t = threadIdx.x;
    int i = blockIdx.x * 256 + t;
    sd[t] = (i < n) ? a[i] : 0;
    __syncthreads();
    for (int off = 128; off > 0; off >>= 1) {
        if (t < off) sd[t] += sd[t + off];
        __syncthreads();
    }
    if (t == 0) bsum[blockIdx.x] = sd[0];
}

__global__ __launch_bounds__(256) void ks2(int* __restrict__ bsum, int nb) {
    __shared__ int sd[256];
    const int t = threadIdx.x;
    sd[t] = (t < nb) ? bsum[t] : 0;
    __syncthreads();
    for (int off = 1; off < 256; off <<= 1) {
        int v = (t >= off) ? sd[t - off] : 0;
        __syncthreads();
        sd[t] += v;
        __syncthreads();
    }
    if (t < nb) bsum[t] = sd[t];
}

__global__ __launch_bounds__(256) void ks3(const int* __restrict__ bsum,
                                           int* __restrict__ start, int* __restrict__ fill, int n) {
    __shared__ int sd[256];
    const int t = threadIdx.x;
    const int i = blockIdx.x * 256 + t;
    sd[t] = (i < n) ? start[i] : 0;
    __syncthreads();
    for (int off = 1; off < 256; off <<= 1) {
        int v = (t >= off) ? sd[t - off] : 0;
        __syncthreads();
        sd[t] += v;
        __syncthreads();
    }
    const int off0 = (blockIdx.x > 0) ? bsum[blockIdx.x - 1] : 0;
    const int val = sd[t] + off0;
    if (i < n) start[i] = val;
    if (i < N_NODES) fill[i] = val;
}

// build CSR order: perm[p] = edge id; pre-gather src/dst into CSR order
__global__ void kpos(const int* __restrict__ dst, const int* __restrict__ src,
                     int* __restrict__ fill, int* __restrict__ perm,
                     int* __restrict__ srcp, int* __restrict__ dstp) {
    int e = blockIdx.x * blockDim.x + threadIdx.x;
    if (e < N_EDGES) {
        int d = dst[e];
        int p = atomicAdd(&fill[d], 1);
        perm[p] = e;
        srcp[p] = src[e];
        dstp[p] = d;
    }
}

// =============== prep: out = nf (acc init) + nf16t transposed bf16 copy ======
// nf16t[node][lm*8+nt] = bf16(nf[node][nt*16+lm]) -> one u16x8 per (row,lane)
// in the fused gather, in exactly MFMA C-fragment column order.
__global__ __launch_bounds__(256) void k_prep(const float* __restrict__ nf,
                                              float* __restrict__ out,
                                              unsigned short* __restrict__ nf16t) {
    const int tid = threadIdx.x;
    const int lm = tid & 15;
    const int node = blockIdx.x * 16 + (tid >> 4);
    if (node >= N_NODES) return;
    const float* nrow = nf + (size_t)node * D_NODE;
    float* orow = out + (size_t)node * D_NODE;
    // acc init (coalesced within the 16-thread group)
    f32x4 y0 = *(const f32x4*)(nrow + lm * 8);
    f32x4 y1 = *(const f32x4*)(nrow + lm * 8 + 4);
    *(f32x4*)(orow + lm * 8) = y0;
    *(f32x4*)(orow + lm * 8 + 4) = y1;
    // transposed bf16 row (reads hit L1; write is a coalesced 16B per thread)
    u16x8 tv;
#pragma unroll
    for (int nt = 0; nt < 8; ++nt) tv[nt] = f2bf(nrow[nt * 16 + lm]);
    *(u16x8*)(nf16t + (size_t)node * D_NODE + lm * 8) = tv;
}

// =============== fused: edge MLP (CSR order) + inline segment reduce =========
// 256 threads, 4 waves, 4 tiles of 16 CSR-ordered edges per wave.
// nf gather: ONE u16x8 (16B contiguous) per row per lane from nf16t.
__global__ __launch_bounds__(256) void k_edge_fused(
    const float* __restrict__ ef, const unsigned short* __restrict__ nf16t,
    const float* __restrict__ W0, const float* __restrict__ b0,
    const float* __restrict__ W1, const float* __restrict__ b1,
    const int* __restrict__ perm, const int* __restrict__ srcp,
    const int* __restrict__ dstp, float* __restrict__ out)
{
    __shared__ unsigned short w0f[2 * 4 * 64 * 8];           // 8 KB
    __shared__ unsigned short w1f[2 * 8 * 64 * 8];           // 16 KB
    __shared__ __align__(16) unsigned short hT[4][16][72];   // layer-1 transpose
    __shared__ __align__(16) unsigned short mT[4][16][136];  // message tile

    const int tid = threadIdx.x;
    for (int f = tid; f < 4096; f += 256) {
        int j = f & 7, lane = (f >> 3) & 63, nt = (f >> 9) & 3, ks = (f >> 11) & 1;
        int k = ks * 32 + ((lane >> 4) << 2) + (j & 3) + ((j & 4) << 2);
        int n = nt * 16 + (lane & 15);
        w0f[f] = f2bf(W0[k * 64 + n]);
    }
    for (int f = tid; f < 8192; f += 256) {
        int j = f & 7, lane = (f >> 3) & 63, nt = (f >> 9) & 7, ks = (f >> 12) & 1;
        int k = ks * 32 + ((lane >> 4) << 2) + (j & 3) + ((j & 4) << 2);
        int n = nt * 16 + (lane & 15);
        w1f[f] = f2bf(W1[k * 128 + n]);
    }
    __syncthreads();

    const int wv = tid >> 6;
    const int lane = tid & 63;
    const int lm = lane & 15;
    const int lq = lane >> 4;

    float b0r[4], b1r[8];
#pragma unroll
    for (int nt = 0; nt < 4; ++nt) b0r[nt] = b0[nt * 16 + lm];
#pragma unroll
    for (int nt = 0; nt < 8; ++nt) b1r[nt] = b1[nt * 16 + lm];

    const bf16x8* w0v = (const bf16x8*)w0f;
    const bf16x8* w1v = (const bf16x8*)w1f;

    const int wtile0 = (blockIdx.x * 4 + wv) * 4;

    for (int t = 0; t < 4; ++t) {
        const int ebase = (wtile0 + t) * 16;

        // ---- per-row meta (coalesced; lane holds row lm's values) ----
        const int e_m = perm[ebase + lm];
        const int s_m = srcp[ebase + lm];
        const int d_m = dstp[ebase + lm];

        // ---- ef row lm (random 256-B row, fully consumed) ----
        const f32x4* er = (const f32x4*)(ef + (size_t)e_m * D_EDGE);
        f32x4 a0 = er[lq];
        f32x4 a1 = er[4 + lq];
        f32x4 a2 = er[8 + lq];
        f32x4 a3 = er[12 + lq];

        // ---- issue bf16 node-row gathers early (1 x 16B per row per lane) ----
        u16x8 ngb[4];
#pragma unroll
        for (int r = 0; r < 4; ++r) {
            const int s_row = __shfl(s_m, lq * 4 + r);
            ngb[r] = *(const u16x8*)(nf16t + (size_t)s_row * D_NODE + lm * 8);
        }

        bf16x8 af0, af1;
#pragma unroll
        for (int j = 0; j < 4; ++j) {
            af0[j] = (short)f2bf(a0[j]); af0[j + 4] = (short)f2bf(a1[j]);
            af1[j] = (short)f2bf(a2[j]); af1[j + 4] = (short)f2bf(a3[j]);
        }

        // ---- layer 1 ----
        f32x4 h[4];
#pragma unroll
        for (int nt = 0; nt < 4; ++nt) h[nt] = f32x4{0.f, 0.f, 0.f, 0.f};
#pragma unroll
        for (int nt = 0; nt < 4; ++nt) {
            h[nt] = __builtin_amdgcn_mfma_f32_16x16x32_bf16(af0, w0v[(0 * 4 + nt) * 64 + lane], h[nt], 0, 0, 0);
            h[nt] = __builtin_amdgcn_mfma_f32_16x16x32_bf16(af1, w0v[(1 * 4 + nt) * 64 + lane], h[nt], 0, 0, 0);
        }
#pragma unroll
        for (int nt = 0; nt < 4; ++nt)
#pragma unroll
            for (int r = 0; r < 4; ++r) {
                float x = h[nt][r] + b0r[nt];
                hT[wv][lq * 4 + r][nt * 16 + lm] = f2bf(fmaxf(x, 0.f));
            }

        const unsigned short* hrow = &hT[wv][lm][0];
        u16x4 p0 = *(const u16x4*)(hrow + lq * 4);
        u16x4 p1 = *(const u16x4*)(hrow + 16 + lq * 4);
        u16x4 p2 = *(const u16x4*)(hrow + 32 + lq * 4);
        u16x4 p3 = *(const u16x4*)(hrow + 48 + lq * 4);
        bf16x8 g0, g1;
#pragma unroll
        for (int j = 0; j < 4; ++j) {
            g0[j] = (short)p0[j]; g0[j + 4] = (short)p1[j];
            g1[j] = (short)p2[j]; g1[j + 4] = (short)p3[j];
        }

        // ---- layer 2 ----
        f32x4 o[8];
#pragma unroll
        for (int nt = 0; nt < 8; ++nt) o[nt] = f32x4{0.f, 0.f, 0.f, 0.f};
#pragma unroll
        for (int nt = 0; nt < 8; ++nt) {
            o[nt] = __builtin_amdgcn_mfma_f32_16x16x32_bf16(g0, w1v[(0 * 8 + nt) * 64 + lane], o[nt], 0, 0, 0);
            o[nt] = __builtin_amdgcn_mfma_f32_16x16x32_bf16(g1, w1v[(1 * 8 + nt) * 64 + lane], o[nt], 0, 0, 0);
        }

        // ---- combine: e = relu(o+b1); m = relu(x_src + e) -> mT ----
#pragma unroll
        for (int r = 0; r < 4; ++r)
#pragma unroll
            for (int nt = 0; nt < 8; ++nt) {
                float e2 = fmaxf(o[nt][r] + b1r[nt], 0.f);
                float x = e2 + bf2f(ngb[r][nt]);
                mT[wv][lq * 4 + r][nt * 16 + lm] = f2bf(fmaxf(x, 0.f));
            }

        // make mT writes visible/ordered before the cross-lane reads below
        asm volatile("" ::: "memory");
        __syncthreads();   // uniform across block (all waves run t=0..3)

        // ---- inline segment-sum: lane owns cols {lane*2, lane*2+1} ----
        // rows are dst-sorted; flush fp32 partials at boundaries via atomics
        float acc0 = 0.f, acc1 = 0.f;
        int dprev = __shfl(d_m, 0);
#pragma unroll
        for (int r = 0; r < 16; ++r) {
            const int dr = __shfl(d_m, r);
            if (dr != dprev) {                    // wave-uniform condition
                float* orow = out + (size_t)dprev * D_NODE + lane * 2;
                unsafeAtomicAdd(orow, acc0);
                unsafeAtomicAdd(orow + 1, acc1);
                acc0 = 0.f; acc1 = 0.f; dprev = dr;
            }
            const u16x2 v = *(const u16x2*)&mT[wv][r][lane * 2];   // typed load
            acc0 += bf2f(v[0]);
            acc1 += bf2f(v[1]);
        }
        float* orow = out + (size_t)dprev * D_NODE + lane * 2;
        unsafeAtomicAdd(orow, acc0);
        unsafeAtomicAdd(orow + 1, acc1);

        asm volatile("" ::: "memory");   // keep next tile's writes below these reads
    }
}

// =============== kernel: acc init (out = nf), fallback path only =============
__global__ void k_copy(const f32x4* __restrict__ s, f32x4* __restrict__ d, int n4) {
    int stride = gridDim.x * blockDim.x;
    for (int i = blockIdx.x * blockDim.x + threadIdx.x; i < n4; i += stride)
        d[i] = s[i];
}

// =============== fallback path (atomic scatter), known-good ==================
__global__ __launch_bounds__(256) void k_edge(
    const float* __restrict__ ef, const float* __restrict__ nf,
    const float* __restrict__ W0, const float* __restrict__ b0,
    const float* __restrict__ W1, const float* __restrict__ b1,
    const int* __restrict__ src, const int* __restrict__ dst,
    float* __restrict__ acc)
{
    __shared__ unsigned short w0f[2 * 4 * 64 * 8];
    __shared__ unsigned short w1f[2 * 8 * 64 * 8];
    __shared__ unsigned short hT[4][16][72];

    const int tid = threadIdx.x;
    for (int f = tid; f < 4096; f += 256) {
        int j = f & 7, lane = (f >> 3) & 63, nt = (f >> 9) & 3, ks = (f >> 11) & 1;
        int k = ks * 32 + ((lane >> 4) << 2) + (j & 3) + ((j & 4) << 2);
        int n = nt * 16 + (lane & 15);
        w0f[f] = f2bf(W0[k * 64 + n]);
    }
    for (int f = tid; f < 8192; f += 256) {
        int j = f & 7, lane = (f >> 3) & 63, nt = (f >> 9) & 7, ks = (f >> 12) & 1;
        int k = ks * 32 + ((lane >> 4) << 2) + (j & 3) + ((j & 4) << 2);
        int n = nt * 16 + (lane & 15);
        w1f[f] = f2bf(W1[k * 128 + n]);
    }
    __syncthreads();

    const int wv = tid >> 6;
    const int lane = tid & 63;
    const int lm = lane & 15;
    const int lq = lane >> 4;

    float b0r[4], b1r[8];
#pragma unroll
    for (int nt = 0; nt < 4; ++nt) b0r[nt] = b0[nt * 16 + lm];
#pragma unroll
    for (int nt = 0; nt < 8; ++nt) b1r[nt] = b1[nt * 16 + lm];

    const bf16x8* w0v = (const bf16x8*)w0f;
    const bf16x8* w1v = (const bf16x8*)w1f;

    for (int t = 0; t < 4; ++t) {
        const int tile = (blockIdx.x * 4 + wv) * 4 + t;
        const int ebase = tile * 16;

        const f32x4* er = (const f32x4*)(ef + (size_t)(ebase + lm) * D_EDGE);
        f32x4 a0 = er[lq];
        f32x4 a1 = er[4 + lq];
        f32x4 a2 = er[8 + lq];
        f32x4 a3 = er[12 + lq];
        bf16x8 af0, af1;
#pragma unroll
        for (int j = 0; j < 4; ++j) {
            af0[j] = (short)f2bf(a0[j]); af0[j + 4] = (short)f2bf(a1[j]);
            af1[j] = (short)f2bf(a2[j]); af1[j + 4] = (short)f2bf(a3[j]);
        }

        f32x4 h[4];
#pragma unroll
        for (int nt = 0; nt < 4; ++nt) h[nt] = f32x4{0.f, 0.f, 0.f, 0.f};
#pragma unroll
        for (int nt = 0; nt < 4; ++nt) {
            h[nt] = __builtin_amdgcn_mfma_f32_16x16x32_bf16(af0, w0v[(0 * 4 + nt) * 64 + lane], h[nt], 0, 0, 0);
            h[nt] = __builtin_amdgcn_mfma_f32_16x16x32_bf16(af1, w0v[(1 * 4 + nt) * 64 + lane], h[nt], 0, 0, 0);
        }
#pragma unroll
        for (int nt = 0; nt < 4; ++nt)
#pragma unroll
            for (int r = 0; r < 4; ++r) {
                float x = h[nt][r] + b0r[nt];
                hT[wv][lq * 4 + r][nt * 16 + lm] = f2bf(fmaxf(x, 0.f));
            }

        const unsigned short* hrow = &hT[wv][lm][0];
        u16x4 p0 = *(const u16x4*)(hrow + lq * 4);
        u16x4 p1 = *(const u16x4*)(hrow + 16 + lq * 4);
        u16x4 p2 = *(const u16x4*)(hrow + 32 + lq * 4);
        u16x4 p3 = *(const u16x4*)(hrow + 48 + lq * 4);
        bf16x8 g0, g1;
#pragma unroll
        for (int j = 0; j < 4; ++j) {
            g0[j] = (short)p0[j]; g0[j + 4] = (short)p1[j];
            g1[j] = (short)p2[j]; g1[j + 4] = (short)p3[j];
        }

        f32x4 o[8];
#pragma unroll
        for (int nt = 0; nt < 8; ++nt) o[nt] = f32x4{0.f, 0.f, 0.f, 0.f};
#pragma unroll
        for (int nt = 0; nt < 8; ++nt) {
            o[nt] = __builtin_amdgcn_mfma_f32_16x16x32_bf16(g0, w1v[(0 * 8 + nt) * 64 + lane], o[nt], 0, 0, 0);
            o[nt] = __builtin_amdgcn_mfma_f32_16x16x32_bf16(g1, w1v[(1 * 8 + nt) * 64 + lane], o[nt], 0, 0, 0);
        }

        const int e0 = ebase + lq * 4;
        int s_[4], d_[4];
#pragma unroll
        for (int r = 0; r < 4; ++r) { s_[r] = src[e0 + r]; d_[r] = dst[e0 + r]; }
#pragma unroll
        for (int r = 0; r < 4; ++r) {
            const float* nrow = nf + (size_t)s_[r] * D_NODE;
            float* arow = acc + (size_t)d_[r] * D_NODE;
#pragma unroll
            for (int nt = 0; nt < 8; ++nt) {
                float e2 = fmaxf(o[nt][r] + b1r[nt], 0.f);
                float x = e2 + nrow[nt * 16 + lm];
                unsafeAtomicAdd(&arow[nt * 16 + lm], fmaxf(x, 0.f));
            }
        }
    }
}

// =============== kernel: out = acc @ Wa + ba, in place =======================
__global__ __launch_bounds__(256) void k_out(
    const float* __restrict__ Wa, const float* __restrict__ ba,
    float* __restrict__ out)
{
    __shared__ unsigned short waf[4 * 8 * 64 * 8];   // 32 KB

    const int tid = threadIdx.x;
    for (int f = tid; f < 16384; f += 256) {
        int j = f & 7, lane = (f >> 3) & 63, nt = (f >> 9) & 7, ks = (f >> 12) & 3;
        int k = ks * 32 + ((lane >> 4) << 2) + (j & 3) + ((j & 4) << 2);
        int n = nt * 16 + (lane & 15);
        waf[f] = f2bf(Wa[k * 128 + n]);
    }
    __syncthreads();

    const int wv = tid >> 6;
    const int lane = tid & 63;
    const int lm = lane & 15;
    const int lq = lane >> 4;

    const int tile = blockIdx.x * 4 + wv;
    if (tile >= N_NODES / 16) return;
    const int rbase = tile * 16;

    const f32x4* arow = (const f32x4*)(out + (size_t)(rbase + lm) * D_NODE);
    const bf16x8* wav = (const bf16x8*)waf;

    bf16x8 afr[4];
#pragma unroll
    for (int ks = 0; ks < 4; ++ks) {
        f32x4 y0 = arow[ks * 8 + lq];
        f32x4 y1 = arow[ks * 8 + 4 + lq];
#pragma unroll
        for (int j = 0; j < 4; ++j) {
            afr[ks][j] = (short)f2bf(y0[j]);
            afr[ks][j + 4] = (short)f2bf(y1[j]);
        }
    }

    float bar[8];
#pragma unroll
    for (int nt = 0; nt < 8; ++nt) bar[nt] = ba[nt * 16 + lm];

    f32x4 o[8];
#pragma unroll
    for (int nt = 0; nt < 8; ++nt) o[nt] = f32x4{0.f, 0.f, 0.f, 0.f};
#pragma unroll
    for (int ks = 0; ks < 4; ++ks)
#pragma unroll
        for (int nt = 0; nt < 8; ++nt)
            o[nt] = __builtin_amdgcn_mfma_f32_16x16x32_bf16(afr[ks], wav[(ks * 8 + nt) * 64 + lane], o[nt], 0, 0, 0);

#pragma unroll
    for (int nt = 0; nt < 8; ++nt)
#pragma unroll
        for (int r = 0; r < 4; ++r)
            out[(size_t)(rbase + lq * 4 + r) * D_NODE + nt * 16 + lm] = o[nt][r] + bar[nt];
}

extern "C" void kernel_launch(void* const* d_in, const int* in_sizes, int n_in,
                              void* d_out, int out_size, void* d_ws, size_t ws_size,
                              hipStream_t stream) {
    const float* nf = (const float*)d_in[0];
    const float* ef = (const float*)d_in[1];
    const float* W0 = (const float*)d_in[2];
    const float* b0 = (const float*)d_in[3];
    const float* W1 = (const float*)d_in[4];
    const float* b1 = (const float*)d_in[5];
    const float* Wa = (const float*)d_in[6];
    const float* ba = (const float*)d_in[7];
    const int* src = (const int*)d_in[8];
    const int* dst = (const int*)d_in[9];
    float* out = (float*)d_out;

    if (ws_size >= WS_NEED) {
        char* ws = (char*)d_ws;
        int* start = (int*)(ws + START_OFF);
        int* fill  = (int*)(ws + FILL_OFF);
        int* perm  = (int*)(ws + PERM_OFF);
        int* srcp  = (int*)(ws + SRCP_OFF);
        int* dstp  = (int*)(ws + DSTP_OFF);
        unsigned short* nf16t = (unsigned short*)(ws + NF16_OFF);
        int* bsum  = perm;   // scratch reuse: perm not yet written during scan

        const int n_scan = N_NODES + 1;
        const int nb = (n_scan + 255) / 256;   // 196

        // acc init + transposed bf16 node features
        k_prep<<<(N_NODES + 15) / 16, 256, 0, stream>>>(nf, out, nf16t);

        kz<<<(n_scan + 255) / 256, 256, 0, stream>>>(start, n_scan);
        kh<<<(N_EDGES + 255) / 256, 256, 0, stream>>>(dst, start);
        ks1<<<nb, 256, 0, stream>>>(start, bsum, n_scan);
        ks2<<<1, 256, 0, stream>>>(bsum, nb);
        ks3<<<nb, 256, 0, stream>>>(bsum, start, fill, n_scan);
        kpos<<<(N_EDGES + 255) / 256, 256, 0, stream>>>(dst, src, fill, perm, srcp, dstp);

        // fused: edge MLP in CSR order + inline segment reduce -> atomic partials
        k_edge_fused<<<N_EDGES / (16 * 4 * 4), 256, 0, stream>>>(
            ef, nf16t, W0, b0, W1, b1, perm, srcp, dstp, out);
    } else {
        // fallback: atomic scatter path
        k_copy<<<2048, 256, 0, stream>>>((const f32x4*)nf, (f32x4*)out, N_NODES * D_NODE / 4);
        k_edge<<<N_EDGES / (16 * 4 * 4), 256, 0, stream>>>(ef, nf, W0, b0, W1, b1, src, dst, out);
    }

    // out = rst @ Wa + ba (in place)
    k_out<<<(N_NODES / 16 + 3) / 4, 256, 0, stream>>>(Wa, ba, out);
}